// Round 7
// baseline (3859.917 us; speedup 1.0000x reference)
//
#include <hip/hip_runtime.h>
#include <cstdint>
#include <cstddef>

#define B_ 16
#define S_ 512
#define H_ 768
#define L_ 12
#define NH_ 12
#define DH_ 64
#define FF_ 3072
#define NL_ 9
#define QKV_ 2304

typedef _Float16 f16x8 __attribute__((ext_vector_type(8)));
typedef float f32x4 __attribute__((ext_vector_type(4)));

// ---------------- async global->LDS (16B per lane, wave-uniform LDS base) ---
__device__ __forceinline__ void load_lds16(const void* g, void* l) {
  __builtin_amdgcn_global_load_lds(
      (const __attribute__((address_space(1))) unsigned int*)g,
      (__attribute__((address_space(3))) unsigned int*)l, 16, 0, 0);
}

// ---------------- block reduction helpers (blockDim == 256) ----------------
__device__ __forceinline__ float block_sum256(float v, float* red) {
#pragma unroll
  for (int off = 32; off; off >>= 1) v += __shfl_down(v, off);
  __syncthreads();
  if ((threadIdx.x & 63) == 0) red[threadIdx.x >> 6] = v;
  __syncthreads();
  return red[0] + red[1] + red[2] + red[3];
}

// Fast exact-GELU: erf via Abramowitz-Stegun 7.1.26 (|err| < 1.5e-7).
// Phi(x) = x>=0 ? 1-0.5*e : 0.5*e, with e = poly(t)*exp(-u^2), t=1/(1+p*u),
// u=|x|/sqrt(2). exp underflow at large |x| saturates correctly (no clamp).
__device__ __forceinline__ float gelu_f(float x) {
  float au = fabsf(x) * 0.70710678118654752f;
  float t = 1.0f / (1.0f + 0.3275911f * au);
  float p = ((((1.061405429f * t - 1.453152027f) * t + 1.421413741f) * t
              - 0.284496736f) * t + 0.254829592f) * t;
  float e = p * __expf(-au * au);
  float phi = (x >= 0.0f) ? (1.0f - 0.5f * e) : (0.5f * e);
  return x * phi;
}

// ---------------- embeddings + LayerNorm (writes f32 h and f16 hb) ----------
__global__ __launch_bounds__(256) void embed_ln_kernel(
    const int* __restrict__ wid, const int* __restrict__ tpid,
    const float* __restrict__ we, const float* __restrict__ pe,
    const float* __restrict__ te, const float* __restrict__ g,
    const float* __restrict__ bb, float* __restrict__ h,
    _Float16* __restrict__ hb) {
  __shared__ float red[4];
  int tok = blockIdx.x;
  int s = tok & (S_ - 1);
  int w = wid[tok], tp = tpid[tok];
  int t = threadIdx.x;
  float x[3];
#pragma unroll
  for (int i = 0; i < 3; ++i) {
    int j = t + i * 256;
    x[i] = we[(size_t)w * H_ + j] + pe[(size_t)s * H_ + j] + te[(size_t)tp * H_ + j];
  }
  float m = block_sum256(x[0] + x[1] + x[2], red) * (1.0f / H_);
  float d0 = x[0] - m, d1 = x[1] - m, d2 = x[2] - m;
  float var = block_sum256(d0 * d0 + d1 * d1 + d2 * d2, red) * (1.0f / H_);
  float rs = rsqrtf(var + 1e-12f);
#pragma unroll
  for (int i = 0; i < 3; ++i) {
    int j = t + i * 256;
    float v = (x[i] - m) * rs * g[j] + bb[j];
    h[(size_t)tok * H_ + j] = v;
    hb[(size_t)tok * H_ + j] = (_Float16)v;
  }
}

// ---------------- residual add + LayerNorm (updates h, writes hb) -----------
__global__ __launch_bounds__(256) void add_ln_kernel(
    float* __restrict__ h, const float* __restrict__ delta,
    const float* __restrict__ g, const float* __restrict__ bb,
    _Float16* __restrict__ hb) {
  __shared__ float red[4];
  int tok = blockIdx.x;
  int t = threadIdx.x;
  float x[3];
#pragma unroll
  for (int i = 0; i < 3; ++i) {
    int j = t + i * 256;
    x[i] = h[(size_t)tok * H_ + j] + delta[(size_t)tok * H_ + j];
  }
  float m = block_sum256(x[0] + x[1] + x[2], red) * (1.0f / H_);
  float d0 = x[0] - m, d1 = x[1] - m, d2 = x[2] - m;
  float var = block_sum256(d0 * d0 + d1 * d1 + d2 * d2, red) * (1.0f / H_);
  float rs = rsqrtf(var + 1e-12f);
#pragma unroll
  for (int i = 0; i < 3; ++i) {
    int j = t + i * 256;
    float v = (x[i] - m) * rs * g[j] + bb[j];
    h[(size_t)tok * H_ + j] = v;
    hb[(size_t)tok * H_ + j] = (_Float16)v;
  }
}

// ---------------- per-layer weight convert + transpose: f32 [K][N] -> f16 [N][K]
// block 1728 additionally concats qkv bias. 64x64 tiles.
__global__ __launch_bounds__(256) void convert_weights_kernel(
    const float* __restrict__ Wq, const float* __restrict__ Wk,
    const float* __restrict__ Wv, const float* __restrict__ Wo,
    const float* __restrict__ W1, const float* __restrict__ W2,
    _Float16* __restrict__ qT, _Float16* __restrict__ kT,
    _Float16* __restrict__ vT, _Float16* __restrict__ oT,
    _Float16* __restrict__ w1T, _Float16* __restrict__ w2T,
    const float* __restrict__ bq, const float* __restrict__ bk,
    const float* __restrict__ bv, float* __restrict__ qkvb) {
  int id = blockIdx.x;
  int tid = threadIdx.x;
  if (id == 1728) {  // bias concat
    for (int j = tid; j < H_; j += 256) {
      qkvb[j] = bq[j];
      qkvb[H_ + j] = bk[j];
      qkvb[2 * H_ + j] = bv[j];
    }
    return;
  }
  __shared__ float T[64][65];
  const float* src;
  _Float16* dst;
  int K, N, tk, tn;
  if (id < 576) {
    int mat = id / 144, t = id % 144;
    K = 768; N = 768; tk = t / 12; tn = t % 12;
    src = (mat == 0) ? Wq : (mat == 1) ? Wk : (mat == 2) ? Wv : Wo;
    dst = (mat == 0) ? qT : (mat == 1) ? kT : (mat == 2) ? vT : oT;
  } else if (id < 1152) {
    int t = id - 576; K = 768; N = 3072; tk = t / 48; tn = t % 48;
    src = W1; dst = w1T;
  } else {
    int t = id - 1152; K = 3072; N = 768; tk = t / 12; tn = t % 12;
    src = W2; dst = w2T;
  }
  int k0 = tk * 64, n0 = tn * 64;
  {
    int r = tid >> 4, c4 = (tid & 15) * 4;
#pragma unroll
    for (int i = 0; i < 4; ++i) {
      float4 v = *(const float4*)&src[(size_t)(k0 + r + i * 16) * N + n0 + c4];
      T[r + i * 16][c4 + 0] = v.x;
      T[r + i * 16][c4 + 1] = v.y;
      T[r + i * 16][c4 + 2] = v.z;
      T[r + i * 16][c4 + 3] = v.w;
    }
  }
  __syncthreads();
#pragma unroll
  for (int i = 0; i < 2; ++i) {
    int chunk = tid + i * 256;
    int n = chunk >> 3, kc = (chunk & 7) * 8;
    f16x8 o;
#pragma unroll
    for (int j = 0; j < 8; ++j) o[j] = (_Float16)T[kc + j][n];
    *(f16x8*)&dst[(size_t)(n0 + n) * K + k0 + kc] = o;
  }
}

// ---------------- WIDE f16 MFMA GEMM: BM=128 x BN=256, wave tile 128x64 -----
// C = A[M,K] @ Bt[N,K]^T + bias. 256 threads = 4 waves, wave w owns cols
// w*64..w*64+63, all 128 rows (8x4 16x16 frags, acc 128 VGPR). Intensity:
// 42.7 FLOP per LDS byte vs 32 for 64x64 wave tiles. Double-buffered LDS via
// global_load_lds (linear dest), 16B-chunk XOR swizzle (conflict-free, r5),
// stage(t+1) before compute(t), one __syncthreads per K-step.
// OUT: 0 = f32, 1 = f16, 2 = f16 + fast exact GELU
template <int OUT>
__global__ __launch_bounds__(256, 2) void gemm_f16w(
    const _Float16* __restrict__ A, const _Float16* __restrict__ Bt,
    const float* __restrict__ bias, void* __restrict__ Cv,
    int M, int N, int K) {
  __shared__ _Float16 As[2][128 * 32];
  __shared__ _Float16 Bs[2][256 * 32];
  int tid = threadIdx.x;
  int lane = tid & 63, w = tid >> 6;
  int l15 = lane & 15, kb = lane >> 4;
  int swk = (l15 >> 1) & 3;

  // XCD-chunked swizzle (bijective when nwg % 8 == 0; all our grids are)
  int nwg = gridDim.x * gridDim.y;
  int bid = blockIdx.y * gridDim.x + blockIdx.x;
  int swz = bid;
  if ((nwg & 7) == 0) {
    int cpx = nwg >> 3;
    swz = (bid & 7) * cpx + (bid >> 3);
  }
  int bx = swz % gridDim.x, by = swz / gridDim.x;
  int row0 = by * 128, col0 = bx * 256;

  // staging: lane l -> LDS slot l (linear); slot holds logical chunk
  // (l&3)^((l>>3)&3) of row l>>2 within each 16-row issue block.
  int srow = lane >> 2;
  int schunk = (lane & 3) ^ ((lane >> 3) & 3);
  int scol = schunk * 8;
  const _Float16* gA0 = A + (size_t)(row0 + (w * 2 + 0) * 16 + srow) * K + scol;
  const _Float16* gA1 = A + (size_t)(row0 + (w * 2 + 1) * 16 + srow) * K + scol;
  const _Float16* gB0 = Bt + (size_t)(col0 + (w * 4 + 0) * 16 + srow) * K + scol;
  const _Float16* gB1 = Bt + (size_t)(col0 + (w * 4 + 1) * 16 + srow) * K + scol;
  const _Float16* gB2 = Bt + (size_t)(col0 + (w * 4 + 2) * 16 + srow) * K + scol;
  const _Float16* gB3 = Bt + (size_t)(col0 + (w * 4 + 3) * 16 + srow) * K + scol;
  int oA0 = (w * 2 + 0) * 1024, oA1 = (w * 2 + 1) * 1024;
  int oB0 = (w * 4 + 0) * 1024, oB1 = (w * 4 + 1) * 1024;
  int oB2 = (w * 4 + 2) * 1024, oB3 = (w * 4 + 3) * 1024;

  f32x4 acc[8][4] = {};
  int nk = K >> 5;

  // prologue: stage tile 0 into buf 0
  load_lds16(gA0, (char*)&As[0][0] + oA0);
  load_lds16(gA1, (char*)&As[0][0] + oA1);
  load_lds16(gB0, (char*)&Bs[0][0] + oB0);
  load_lds16(gB1, (char*)&Bs[0][0] + oB1);
  load_lds16(gB2, (char*)&Bs[0][0] + oB2);
  load_lds16(gB3, (char*)&Bs[0][0] + oB3);
  __syncthreads();

  for (int t = 0; t < nk; ++t) {
    int cur = t & 1;
    if (t + 1 < nk) {
      int ko = (t + 1) * 32;
      load_lds16(gA0 + ko, (char*)&As[cur ^ 1][0] + oA0);
      load_lds16(gA1 + ko, (char*)&As[cur ^ 1][0] + oA1);
      load_lds16(gB0 + ko, (char*)&Bs[cur ^ 1][0] + oB0);
      load_lds16(gB1 + ko, (char*)&Bs[cur ^ 1][0] + oB1);
      load_lds16(gB2 + ko, (char*)&Bs[cur ^ 1][0] + oB2);
      load_lds16(gB3 + ko, (char*)&Bs[cur ^ 1][0] + oB3);
    }
    int rpos = (kb ^ swk) * 8;
    f16x8 af[8], bf[4];
#pragma unroll
    for (int m = 0; m < 8; ++m)
      af[m] = *(const f16x8*)&As[cur][(m * 16 + l15) * 32 + rpos];
#pragma unroll
    for (int n = 0; n < 4; ++n)
      bf[n] = *(const f16x8*)&Bs[cur][(w * 64 + n * 16 + l15) * 32 + rpos];
#pragma unroll
    for (int m = 0; m < 8; ++m)
#pragma unroll
      for (int n = 0; n < 4; ++n)
        acc[m][n] = __builtin_amdgcn_mfma_f32_16x16x32_f16(af[m], bf[n], acc[m][n], 0, 0, 0);
    __syncthreads();  // drains vmcnt(0): stage(t+1) landed; reads of buf cur done
  }
#pragma unroll
  for (int n = 0; n < 4; ++n) {
    int col = col0 + w * 64 + n * 16 + l15;
    float bv = bias[col];
#pragma unroll
    for (int m = 0; m < 8; ++m) {
      int rowb = row0 + m * 16 + kb * 4;
#pragma unroll
      for (int r = 0; r < 4; ++r) {
        float v = acc[m][n][r] + bv;
        if (OUT == 2) v = gelu_f(v);
        if (OUT == 0)
          ((float*)Cv)[(size_t)(rowb + r) * N + col] = v;
        else
          ((_Float16*)Cv)[(size_t)(rowb + r) * N + col] = (_Float16)v;
      }
    }
  }
}

// ---------------- f16 MFMA GEMM (128x128): tri-buffered counted-vmcnt -------
// Used for the N=768 GEMMs (O-proj, FF2) where BN=256 would starve the grid.
template <int OUT>
__global__ __launch_bounds__(256) void gemm_f16(
    const _Float16* __restrict__ A, const _Float16* __restrict__ Bt,
    const float* __restrict__ bias, void* __restrict__ Cv,
    int M, int N, int K) {
  __shared__ _Float16 As[3][128 * 32];
  __shared__ _Float16 Bs[3][128 * 32];
  int tid = threadIdx.x;
  int lane = tid & 63, w = tid >> 6;
  int wr = w >> 1, wc = w & 1;
  int l15 = lane & 15, kb = lane >> 4;
  int swk = (l15 >> 1) & 3;

  int nwg = gridDim.x * gridDim.y;
  int bid = blockIdx.y * gridDim.x + blockIdx.x;
  int swz = bid;
  if ((nwg & 7) == 0) {
    int cpx = nwg >> 3;
    swz = (bid & 7) * cpx + (bid >> 3);
  }
  int bx = swz % gridDim.x, by = swz / gridDim.x;
  int row0 = by * 128, col0 = bx * 128;

  int srow = lane >> 2;
  int schunk = (lane & 3) ^ ((lane >> 3) & 3);
  int scol = schunk * 8;
  const _Float16* gA0 = A + (size_t)(row0 + (w * 2 + 0) * 16 + srow) * K + scol;
  const _Float16* gA1 = A + (size_t)(row0 + (w * 2 + 1) * 16 + srow) * K + scol;
  const _Float16* gB0 = Bt + (size_t)(col0 + (w * 2 + 0) * 16 + srow) * K + scol;
  const _Float16* gB1 = Bt + (size_t)(col0 + (w * 2 + 1) * 16 + srow) * K + scol;
  int o0 = (w * 2 + 0) * 1024;
  int o1 = (w * 2 + 1) * 1024;

  auto STAGE = [&](int t, int buf) {
    int ko = t * 32;
    load_lds16(gA0 + ko, (char*)&As[buf][0] + o0);
    load_lds16(gA1 + ko, (char*)&As[buf][0] + o1);
    load_lds16(gB0 + ko, (char*)&Bs[buf][0] + o0);
    load_lds16(gB1 + ko, (char*)&Bs[buf][0] + o1);
  };

  f32x4 acc[4][4] = {};
  int nk = K >> 5;

  STAGE(0, 0);
  STAGE(1, 1);
  asm volatile("s_waitcnt vmcnt(4)" ::: "memory");
  __builtin_amdgcn_s_barrier();
  __builtin_amdgcn_sched_barrier(0);

  for (int t = 0; t < nk; ++t) {
    int buf = t % 3;
    if (t + 2 < nk) {
      STAGE(t + 2, (t + 2) % 3);
      asm volatile("s_waitcnt vmcnt(8)" ::: "memory");
    } else if (t + 1 < nk) {
      asm volatile("s_waitcnt vmcnt(4)" ::: "memory");
    } else {
      asm volatile("s_waitcnt vmcnt(0)" ::: "memory");
    }
    __builtin_amdgcn_s_barrier();
    __builtin_amdgcn_sched_barrier(0);
    f16x8 af[4], bf[4];
    int rpos = (kb ^ swk) * 8;
#pragma unroll
    for (int m = 0; m < 4; ++m)
      af[m] = *(const f16x8*)&As[buf][(wr * 64 + m * 16 + l15) * 32 + rpos];
#pragma unroll
    for (int n = 0; n < 4; ++n)
      bf[n] = *(const f16x8*)&Bs[buf][(wc * 64 + n * 16 + l15) * 32 + rpos];
#pragma unroll
    for (int m = 0; m < 4; ++m)
#pragma unroll
      for (int n = 0; n < 4; ++n)
        acc[m][n] = __builtin_amdgcn_mfma_f32_16x16x32_f16(af[m], bf[n], acc[m][n], 0, 0, 0);
    asm volatile("s_waitcnt lgkmcnt(0)" ::: "memory");
    __builtin_amdgcn_sched_barrier(0);
    __builtin_amdgcn_s_barrier();
  }
#pragma unroll
  for (int n = 0; n < 4; ++n) {
    int col = col0 + wc * 64 + n * 16 + l15;
    float bv = bias[col];
#pragma unroll
    for (int m = 0; m < 4; ++m) {
      int rowb = row0 + wr * 64 + m * 16 + kb * 4;
#pragma unroll
      for (int r = 0; r < 4; ++r) {
        float v = acc[m][n][r] + bv;
        if (OUT == 2) v = gelu_f(v);
        if (OUT == 0)
          ((float*)Cv)[(size_t)(rowb + r) * N + col] = v;
        else
          ((_Float16*)Cv)[(size_t)(rowb + r) * N + col] = (_Float16)v;
      }
    }
  }
}

// ---------------- V transpose per head: qkv v-cols -> vt [b*12+h][64][512] --
__global__ __launch_bounds__(256) void vtrans_kernel(
    const _Float16* __restrict__ v, int RS, _Float16* __restrict__ vt) {
  __shared__ _Float16 T[64][72];
  int s0 = blockIdx.x * 64;
  int bh = blockIdx.y;
  int b = bh / NH_, h = bh % NH_;
  int tid = threadIdx.x;
#pragma unroll
  for (int i = 0; i < 2; ++i) {
    int chunk = tid + i * 256;
    int s = chunk >> 3, dc = (chunk & 7) * 8;
    *(f16x8*)&T[s][dc] = *(const f16x8*)&v[(size_t)(b * S_ + s0 + s) * RS + h * DH_ + dc];
  }
  __syncthreads();
#pragma unroll
  for (int i = 0; i < 2; ++i) {
    int chunk = tid + i * 256;
    int d = chunk >> 3, sc = (chunk & 7) * 8;
    f16x8 o;
#pragma unroll
    for (int j = 0; j < 8; ++j) o[j] = T[sc + j][d];
    *(f16x8*)&vt[(size_t)(bh * DH_ + d) * S_ + s0 + sc] = o;
  }
}

// ---------------- fused flash attention, f16 MFMA ---------------------------
__global__ __launch_bounds__(256) void flash_attn_kernel(
    const _Float16* __restrict__ q, const _Float16* __restrict__ k,
    const _Float16* __restrict__ vt, int RS, const int* __restrict__ mask,
    _Float16* __restrict__ ctx) {
  __shared__ _Float16 Ks[128 * 72];
  __shared__ _Float16 Vs[64 * 136];
  __shared__ _Float16 Ps[4][16 * 136];
  __shared__ float biasz[S_];
  int qt = blockIdx.x, h = blockIdx.y, b = blockIdx.z;
  int tid = threadIdx.x, lane = tid & 63, w = tid >> 6;
  int l15 = lane & 15, kb = lane >> 4;
  const float C = 0.125f * 1.44269504088896f;

  for (int i = tid; i < S_; i += 256)
    biasz[i] = (1.0f - (float)mask[b * S_ + i]) * (-1e9f * C);

  int qrow = b * S_ + qt * 64 + w * 16 + l15;
  f16x8 qf[2];
  qf[0] = *(const f16x8*)&q[(size_t)qrow * RS + h * DH_ + kb * 8];
  qf[1] = *(const f16x8*)&q[(size_t)qrow * RS + h * DH_ + 32 + kb * 8];

  auto loadKV = [&](int kt, f16x8* rk, f16x8* rv) {
#pragma unroll
    for (int i = 0; i < 4; ++i) {
      int idx = tid + i * 256;
      int r = idx >> 3, c = idx & 7;
      rk[i] = *(const f16x8*)&k[(size_t)(b * S_ + kt * 128 + r) * RS + h * DH_ + c * 8];
      int d = idx >> 4, c2 = idx & 15;
      rv[i] = *(const f16x8*)&vt[(size_t)((b * NH_ + h) * DH_ + d) * S_ + kt * 128 + c2 * 8];
    }
  };

  float m_run[4], l_run[4];
  f32x4 o[4] = {};
#pragma unroll
  for (int r = 0; r < 4; ++r) { m_run[r] = -1e30f; l_run[r] = 0.f; }

  f16x8 rk[4], rv[4];
  loadKV(0, rk, rv);
  for (int kt = 0; kt < 4; ++kt) {
    __syncthreads();
#pragma unroll
    for (int i = 0; i < 4; ++i) {
      int idx = tid + i * 256;
      int r = idx >> 3, c = idx & 7;
      *(f16x8*)&Ks[r * 72 + c * 8] = rk[i];
      int d = idx >> 4, c2 = idx & 15;
      *(f16x8*)&Vs[d * 136 + c2 * 8] = rv[i];
    }
    __syncthreads();
    if (kt < 3) loadKV(kt + 1, rk, rv);
    f32x4 s[8];
#pragma unroll
    for (int nf = 0; nf < 8; ++nf) {
      f16x8 b0 = *(const f16x8*)&Ks[(nf * 16 + l15) * 72 + kb * 8];
      f16x8 b1 = *(const f16x8*)&Ks[(nf * 16 + l15) * 72 + 32 + kb * 8];
      f32x4 z = {};
      z = __builtin_amdgcn_mfma_f32_16x16x32_f16(qf[0], b0, z, 0, 0, 0);
      z = __builtin_amdgcn_mfma_f32_16x16x32_f16(qf[1], b1, z, 0, 0, 0);
      s[nf] = z;
    }
    float zb[8];
#pragma unroll
    for (int nf = 0; nf < 8; ++nf) zb[nf] = biasz[kt * 128 + nf * 16 + l15];
    float pw[8][4];
    float corr[4];
#pragma unroll
    for (int r = 0; r < 4; ++r) {
      float mx = -1e30f;
#pragma unroll
      for (int nf = 0; nf < 8; ++nf) mx = fmaxf(mx, s[nf][r] * C + zb[nf]);
#pragma unroll
      for (int d = 1; d < 16; d <<= 1) mx = fmaxf(mx, __shfl_xor(mx, d));
      float mnew = fmaxf(m_run[r], mx);
      float cr = exp2f(m_run[r] - mnew);
      m_run[r] = mnew;
      corr[r] = cr;
      float sum = 0.f;
#pragma unroll
      for (int nf = 0; nf < 8; ++nf) {
        float pv = exp2f(s[nf][r] * C + zb[nf] - mnew);
        pw[nf][r] = pv;
        sum += pv;
      }
#pragma unroll
      for (int d = 1; d < 16; d <<= 1) sum += __shfl_xor(sum, d);
      l_run[r] = l_run[r] * cr + sum;
    }
#pragma unroll
    for (int nf2 = 0; nf2 < 4; ++nf2)
#pragma unroll
      for (int r = 0; r < 4; ++r) o[nf2][r] *= corr[r];
#pragma unroll
    for (int nf = 0; nf < 8; ++nf)
#pragma unroll
      for (int r = 0; r < 4; ++r)
        Ps[w][(kb * 4 + r) * 136 + nf * 16 + l15] = (_Float16)pw[nf][r];
#pragma unroll
    for (int ks = 0; ks < 4; ++ks) {
      f16x8 pa = *(const f16x8*)&Ps[w][l15 * 136 + ks * 32 + kb * 8];
#pragma unroll
      for (int nf2 = 0; nf2 < 4; ++nf2) {
        f16x8 vb2 = *(const f16x8*)&Vs[(nf2 * 16 + l15) * 136 + ks * 32 + kb * 8];
        o[nf2] = __builtin_amdgcn_mfma_f32_16x16x32_f16(pa, vb2, o[nf2], 0, 0, 0);
      }
    }
  }
  float inv[4];
#pragma unroll
  for (int r = 0; r < 4; ++r) inv[r] = 1.0f / fmaxf(l_run[r], 1e-37f);
#pragma unroll
  for (int nf2 = 0; nf2 < 4; ++nf2)
#pragma unroll
    for (int r = 0; r < 4; ++r) {
      int row = b * S_ + qt * 64 + w * 16 + kb * 4 + r;
      ctx[(size_t)row * H_ + h * DH_ + nf2 * 16 + l15] = (_Float16)(o[nf2][r] * inv[r]);
    }
}

// ---------------- valid-token compaction ----------------
__global__ void compact_idx_kernel(const int* __restrict__ valid, int* __restrict__ dest) {
  int b = threadIdx.x;
  if (b >= B_) return;
  int cnt = 0;
  for (int s = 0; s < S_; ++s) {
    int vv = valid[b * S_ + s];
    dest[b * S_ + s] = vv ? cnt : -1;
    cnt += vv;
  }
}

__global__ __launch_bounds__(256) void scatter_kernel(
    const float* __restrict__ h, const int* __restrict__ dest,
    float* __restrict__ compact) {
  int tok = blockIdx.x;
  int d = dest[tok];
  if (d < 0) return;
  int b = tok >> 9;
  size_t src = (size_t)tok * H_;
  size_t dst = ((size_t)(b * S_ + d)) * H_;
  for (int j = threadIdx.x; j < H_; j += 256) compact[dst + j] = h[src + j];
}

// ---------------- classifier + softmax: one wave per token ----------------
__global__ __launch_bounds__(256) void cls_kernel(
    const float* __restrict__ x, const float* __restrict__ W,
    const float* __restrict__ bias2, float* __restrict__ out) {
  int lane = threadIdx.x & 63, wv = threadIdx.x >> 6;
  int tok = blockIdx.x * 4 + wv;
  float acc[NL_] = {};
  for (int hh = lane; hh < H_; hh += 64) {
    float xv = x[(size_t)tok * H_ + hh];
#pragma unroll
    for (int n = 0; n < NL_; ++n) acc[n] = fmaf(xv, W[hh * NL_ + n], acc[n]);
  }
#pragma unroll
  for (int n = 0; n < NL_; ++n) {
#pragma unroll
    for (int off = 32; off; off >>= 1) acc[n] += __shfl_down(acc[n], off);
  }
  if (lane == 0) {
    float vls[NL_], mx = -1e30f;
#pragma unroll
    for (int n = 0; n < NL_; ++n) {
      vls[n] = acc[n] + bias2[n];
      mx = fmaxf(mx, vls[n]);
    }
    float s = 0.f;
#pragma unroll
    for (int n = 0; n < NL_; ++n) {
      vls[n] = expf(vls[n] - mx);
      s += vls[n];
    }
    float inv = 1.0f / s;
#pragma unroll
    for (int n = 0; n < NL_; ++n) out[(size_t)tok * NL_ + n] = vls[n] * inv;
  }
}

extern "C" void kernel_launch(void* const* d_in, const int* in_sizes, int n_in,
                              void* d_out, int out_size, void* d_ws, size_t ws_size,
                              hipStream_t stream) {
  const int* wid = (const int*)d_in[0];
  const int* mask = (const int*)d_in[1];
  const int* tpid = (const int*)d_in[2];
  const int* valid = (const int*)d_in[3];
  const float* we = (const float*)d_in[4];
  const float* pe = (const float*)d_in[5];
  const float* te = (const float*)d_in[6];
  const float* eg = (const float*)d_in[7];
  const float* eb = (const float*)d_in[8];
  const float* Wq = (const float*)d_in[9];
  const float* bq = (const float*)d_in[10];
  const float* Wk = (const float*)d_in[11];
  const float* bk = (const float*)d_in[12];
  const float* Wv = (const float*)d_in[13];
  const float* bv = (const float*)d_in[14];
  const float* Wo = (const float*)d_in[15];
  const float* bo = (const float*)d_in[16];
  const float* g1 = (const float*)d_in[17];
  const float* gb1 = (const float*)d_in[18];
  const float* W1 = (const float*)d_in[19];
  const float* bf1 = (const float*)d_in[20];
  const float* W2 = (const float*)d_in[21];
  const float* bf2 = (const float*)d_in[22];
  const float* g2 = (const float*)d_in[23];
  const float* gb2 = (const float*)d_in[24];
  const float* cW = (const float*)d_in[25];
  const float* cb = (const float*)d_in[26];
  float* out = (float*)d_out;

  const size_t TOK = (size_t)B_ * S_;  // 8192
  char* ws = (char*)d_ws;
  float* h = (float*)ws;                              // 25,165,824 B
  _Float16* hb = (_Float16*)(ws + 25165824);          // 12,582,912 B
  float* t1 = (float*)(ws + 37748736);                // 25,165,824 B (O/FF2 out, compact)
  char* un1 = ws + 62914560;                          // 50,331,648 B union
  _Float16* qkv = (_Float16*)un1;                     // [8192][2304] = 37,748,736 B
  _Float16* vt = (_Float16*)(un1 + 37748736);         // 12,582,912 B
  _Float16* ffh = (_Float16*)un1;                     // overlays qkv/vt after attn
  _Float16* ctx = (_Float16*)(ws + 113246208);        // 12,582,912 B
  char* wbuf = ws + 125829120;                        // 14,155,776 B
  _Float16* wqT = (_Float16*)wbuf;                    // [2304][768] fused (q,k,v rows)
  _Float16* wkT = (_Float16*)(wbuf + 1179648);
  _Float16* wvT = (_Float16*)(wbuf + 2359296);
  _Float16* woT = (_Float16*)(wbuf + 3538944);
  _Float16* w1T = (_Float16*)(wbuf + 4718592);
  _Float16* w2T = (_Float16*)(wbuf + 9437184);
  int* dest = (int*)(ws + 139984896);                 // 32,768 B
  float* qkvb = (float*)(ws + 140017664);             // 9,216 B

  dim3 blk(256);
  embed_ln_kernel<<<dim3((unsigned)TOK), blk, 0, stream>>>(wid, tpid, we, pe, te, eg, eb, h, hb);

  dim3 gQKVw(QKV_ / 256, TOK / 128);  // (9, 64)  = 576 blocks (wide)
  dim3 gF1w(FF_ / 256, TOK / 128);    // (12, 64) = 768 blocks (wide)
  dim3 gH(H_ / 128, TOK / 128);       // (6, 64)  = 384 blocks
  for (int l = 0; l < L_; ++l) {
    convert_weights_kernel<<<dim3(1729), blk, 0, stream>>>(
        Wq + (size_t)l * H_ * H_, Wk + (size_t)l * H_ * H_,
        Wv + (size_t)l * H_ * H_, Wo + (size_t)l * H_ * H_,
        W1 + (size_t)l * H_ * FF_, W2 + (size_t)l * FF_ * H_,
        wqT, wkT, wvT, woT, w1T, w2T,
        bq + l * H_, bk + l * H_, bv + l * H_, qkvb);
    gemm_f16w<1><<<gQKVw, blk, 0, stream>>>(hb, wqT, qkvb, qkv, (int)TOK, QKV_, H_);
    vtrans_kernel<<<dim3(S_ / 64, B_ * NH_), blk, 0, stream>>>(qkv + 2 * H_, QKV_, vt);
    flash_attn_kernel<<<dim3(S_ / 64, NH_, B_), blk, 0, stream>>>(
        qkv, qkv + H_, vt, QKV_, mask, ctx);
    gemm_f16<0><<<gH, blk, 0, stream>>>(ctx, woT, bo + l * H_, t1, (int)TOK, H_, H_);
    add_ln_kernel<<<dim3((unsigned)TOK), blk, 0, stream>>>(h, t1, g1 + l * H_, gb1 + l * H_, hb);
    gemm_f16w<2><<<gF1w, blk, 0, stream>>>(hb, w1T, bf1 + l * FF_, ffh, (int)TOK, FF_, H_);
    gemm_f16<0><<<gH, blk, 0, stream>>>(ffh, w2T, bf2 + l * H_, t1, (int)TOK, H_, FF_);
    add_ln_kernel<<<dim3((unsigned)TOK), blk, 0, stream>>>(h, t1, g2 + l * H_, gb2 + l * H_, hb);
  }

  compact_idx_kernel<<<1, 64, 0, stream>>>(valid, dest);
  hipMemsetAsync(t1, 0, TOK * H_ * sizeof(float), stream);
  scatter_kernel<<<dim3((unsigned)TOK), blk, 0, stream>>>(h, dest, t1);
  cls_kernel<<<dim3((unsigned)(TOK / 4)), blk, 0, stream>>>(t1, cW, cb, out);
}

// Round 8
// 3660.756 us; speedup vs baseline: 1.0544x; 1.0544x over previous
//
#include <hip/hip_runtime.h>
#include <cstdint>
#include <cstddef>

#define B_ 16
#define S_ 512
#define H_ 768
#define L_ 12
#define NH_ 12
#define DH_ 64
#define FF_ 3072
#define NL_ 9
#define QKV_ 2304

typedef _Float16 f16x8 __attribute__((ext_vector_type(8)));
typedef _Float16 f16x4 __attribute__((ext_vector_type(4)));
typedef float f32x4 __attribute__((ext_vector_type(4)));

// ---------------- async global->LDS (16B per lane, wave-uniform LDS base) ---
__device__ __forceinline__ void load_lds16(const void* g, void* l) {
  __builtin_amdgcn_global_load_lds(
      (const __attribute__((address_space(1))) unsigned int*)g,
      (__attribute__((address_space(3))) unsigned int*)l, 16, 0, 0);
}

// ---------------- block reduction helpers ----------------
__device__ __forceinline__ float block_sum256(float v, float* red) {
#pragma unroll
  for (int off = 32; off; off >>= 1) v += __shfl_down(v, off);
  __syncthreads();
  if ((threadIdx.x & 63) == 0) red[threadIdx.x >> 6] = v;
  __syncthreads();
  return red[0] + red[1] + red[2] + red[3];
}

// 192-thread (3-wave) block sum
__device__ __forceinline__ float block_sum192(float v, float* red) {
#pragma unroll
  for (int off = 32; off; off >>= 1) v += __shfl_down(v, off);
  __syncthreads();
  if ((threadIdx.x & 63) == 0) red[threadIdx.x >> 6] = v;
  __syncthreads();
  return red[0] + red[1] + red[2];
}

// Fast exact-GELU: erf via Abramowitz-Stegun 7.1.26 (|err| < 1.5e-7).
__device__ __forceinline__ float gelu_f(float x) {
  float au = fabsf(x) * 0.70710678118654752f;
  float t = 1.0f / (1.0f + 0.3275911f * au);
  float p = ((((1.061405429f * t - 1.453152027f) * t + 1.421413741f) * t
              - 0.284496736f) * t + 0.254829592f) * t;
  float e = p * __expf(-au * au);
  float phi = (x >= 0.0f) ? (1.0f - 0.5f * e) : (0.5f * e);
  return x * phi;
}

// ---------------- embeddings + LayerNorm (writes f16 hb) --------------------
__global__ __launch_bounds__(256) void embed_ln_kernel(
    const int* __restrict__ wid, const int* __restrict__ tpid,
    const float* __restrict__ we, const float* __restrict__ pe,
    const float* __restrict__ te, const float* __restrict__ g,
    const float* __restrict__ bb, _Float16* __restrict__ hb) {
  __shared__ float red[4];
  int tok = blockIdx.x;
  int s = tok & (S_ - 1);
  int w = wid[tok], tp = tpid[tok];
  int t = threadIdx.x;
  float x[3];
#pragma unroll
  for (int i = 0; i < 3; ++i) {
    int j = t + i * 256;
    x[i] = we[(size_t)w * H_ + j] + pe[(size_t)s * H_ + j] + te[(size_t)tp * H_ + j];
  }
  float m = block_sum256(x[0] + x[1] + x[2], red) * (1.0f / H_);
  float d0 = x[0] - m, d1 = x[1] - m, d2 = x[2] - m;
  float var = block_sum256(d0 * d0 + d1 * d1 + d2 * d2, red) * (1.0f / H_);
  float rs = rsqrtf(var + 1e-12f);
#pragma unroll
  for (int i = 0; i < 3; ++i) {
    int j = t + i * 256;
    float v = (x[i] - m) * rs * g[j] + bb[j];
    hb[(size_t)tok * H_ + j] = (_Float16)v;
  }
}

// ---------------- pure LayerNorm on f16 x -> f16 hb (192 thr, f16x4) --------
__global__ __launch_bounds__(192) void ln_f16_kernel(
    const _Float16* __restrict__ x, const float* __restrict__ g,
    const float* __restrict__ bb, _Float16* __restrict__ hb) {
  __shared__ float red[3];
  int tok = blockIdx.x;
  int t = threadIdx.x;
  int j = t * 4;
  f16x4 xv = *(const f16x4*)&x[(size_t)tok * H_ + j];
  float v0 = (float)xv[0], v1 = (float)xv[1], v2 = (float)xv[2], v3 = (float)xv[3];
  float m = block_sum192(v0 + v1 + v2 + v3, red) * (1.0f / H_);
  float d0 = v0 - m, d1 = v1 - m, d2 = v2 - m, d3 = v3 - m;
  __syncthreads();  // red reuse
  float var = block_sum192(d0 * d0 + d1 * d1 + d2 * d2 + d3 * d3, red) * (1.0f / H_);
  float rs = rsqrtf(var + 1e-12f);
  float4 gv = *(const float4*)&g[j];
  float4 bv = *(const float4*)&bb[j];
  f16x4 o;
  o[0] = (_Float16)(d0 * rs * gv.x + bv.x);
  o[1] = (_Float16)(d1 * rs * gv.y + bv.y);
  o[2] = (_Float16)(d2 * rs * gv.z + bv.z);
  o[3] = (_Float16)(d3 * rs * gv.w + bv.w);
  *(f16x4*)&hb[(size_t)tok * H_ + j] = o;
}

// ---------------- per-layer weight convert + transpose: f32 [K][N] -> f16 [N][K]
// block 1728 additionally concats qkv bias. 64x64 tiles.
__global__ __launch_bounds__(256) void convert_weights_kernel(
    const float* __restrict__ Wq, const float* __restrict__ Wk,
    const float* __restrict__ Wv, const float* __restrict__ Wo,
    const float* __restrict__ W1, const float* __restrict__ W2,
    _Float16* __restrict__ qT, _Float16* __restrict__ kT,
    _Float16* __restrict__ vT, _Float16* __restrict__ oT,
    _Float16* __restrict__ w1T, _Float16* __restrict__ w2T,
    const float* __restrict__ bq, const float* __restrict__ bk,
    const float* __restrict__ bv, float* __restrict__ qkvb) {
  int id = blockIdx.x;
  int tid = threadIdx.x;
  if (id == 1728) {  // bias concat
    for (int j = tid; j < H_; j += 256) {
      qkvb[j] = bq[j];
      qkvb[H_ + j] = bk[j];
      qkvb[2 * H_ + j] = bv[j];
    }
    return;
  }
  __shared__ float T[64][65];
  const float* src;
  _Float16* dst;
  int K, N, tk, tn;
  if (id < 576) {
    int mat = id / 144, t = id % 144;
    K = 768; N = 768; tk = t / 12; tn = t % 12;
    src = (mat == 0) ? Wq : (mat == 1) ? Wk : (mat == 2) ? Wv : Wo;
    dst = (mat == 0) ? qT : (mat == 1) ? kT : (mat == 2) ? vT : oT;
  } else if (id < 1152) {
    int t = id - 576; K = 768; N = 3072; tk = t / 48; tn = t % 48;
    src = W1; dst = w1T;
  } else {
    int t = id - 1152; K = 3072; N = 768; tk = t / 12; tn = t % 12;
    src = W2; dst = w2T;
  }
  int k0 = tk * 64, n0 = tn * 64;
  {
    int r = tid >> 4, c4 = (tid & 15) * 4;
#pragma unroll
    for (int i = 0; i < 4; ++i) {
      float4 v = *(const float4*)&src[(size_t)(k0 + r + i * 16) * N + n0 + c4];
      T[r + i * 16][c4 + 0] = v.x;
      T[r + i * 16][c4 + 1] = v.y;
      T[r + i * 16][c4 + 2] = v.z;
      T[r + i * 16][c4 + 3] = v.w;
    }
  }
  __syncthreads();
#pragma unroll
  for (int i = 0; i < 2; ++i) {
    int chunk = tid + i * 256;
    int n = chunk >> 3, kc = (chunk & 7) * 8;
    f16x8 o;
#pragma unroll
    for (int j = 0; j < 8; ++j) o[j] = (_Float16)T[kc + j][n];
    *(f16x8*)&dst[(size_t)(n0 + n) * K + k0 + kc] = o;
  }
}

// ---------------- f16 MFMA GEMM, 2-phase dbuf + LDS chunk swizzle (round-5) -
// C = A[M,K] @ Bt[N,K]^T + bias. 128x128 tile, BK=32, 256 threads (2x2 waves,
// 64x64/wave). Double-buffered LDS staged by global_load_lds (linear dest);
// 16B chunks XOR-swizzled both sides (conflict-free). stage(t+1) issued
// BEFORE compute(t); ONE barrier per K-step.
// OUT: 1 = f16+bias, 2 = f16+bias+GELU, 3 = f16+bias+residual(hres f16)
template <int OUT>
__global__ __launch_bounds__(256) void gemm_f16(
    const _Float16* __restrict__ A, const _Float16* __restrict__ Bt,
    const float* __restrict__ bias, void* __restrict__ Cv,
    int M, int N, int K, const _Float16* __restrict__ hres) {
  __shared__ _Float16 As[2][128 * 32];
  __shared__ _Float16 Bs[2][128 * 32];
  int tid = threadIdx.x;
  int lane = tid & 63, w = tid >> 6;
  int wr = w >> 1, wc = w & 1;
  int l15 = lane & 15, kb = lane >> 4;
  int swk = (l15 >> 1) & 3;  // read-side swizzle term

  // XCD-chunked swizzle (bijective when nwg % 8 == 0; all our grids are)
  int nwg = gridDim.x * gridDim.y;
  int bid = blockIdx.y * gridDim.x + blockIdx.x;
  int swz = bid;
  if ((nwg & 7) == 0) {
    int cpx = nwg >> 3;
    swz = (bid & 7) * cpx + (bid >> 3);
  }
  int bx = swz % gridDim.x, by = swz / gridDim.x;
  int row0 = by * 128, col0 = bx * 128;

  int srow = lane >> 2;
  int schunk = (lane & 3) ^ ((lane >> 3) & 3);
  int scol = schunk * 8;
  const _Float16* gA0 = A + (size_t)(row0 + (w * 2 + 0) * 16 + srow) * K + scol;
  const _Float16* gA1 = A + (size_t)(row0 + (w * 2 + 1) * 16 + srow) * K + scol;
  const _Float16* gB0 = Bt + (size_t)(col0 + (w * 2 + 0) * 16 + srow) * K + scol;
  const _Float16* gB1 = Bt + (size_t)(col0 + (w * 2 + 1) * 16 + srow) * K + scol;
  int o0 = (w * 2 + 0) * 1024;
  int o1 = (w * 2 + 1) * 1024;

  f32x4 acc[4][4] = {};
  int nk = K >> 5;

  load_lds16(gA0, (char*)&As[0][0] + o0);
  load_lds16(gA1, (char*)&As[0][0] + o1);
  load_lds16(gB0, (char*)&Bs[0][0] + o0);
  load_lds16(gB1, (char*)&Bs[0][0] + o1);
  __syncthreads();

  for (int kt = 0; kt < nk; ++kt) {
    int cur = kt & 1;
    if (kt + 1 < nk) {
      int ko = (kt + 1) * 32;
      load_lds16(gA0 + ko, (char*)&As[cur ^ 1][0] + o0);
      load_lds16(gA1 + ko, (char*)&As[cur ^ 1][0] + o1);
      load_lds16(gB0 + ko, (char*)&Bs[cur ^ 1][0] + o0);
      load_lds16(gB1 + ko, (char*)&Bs[cur ^ 1][0] + o1);
    }
    f16x8 af[4], bf[4];
    int rpos = (kb ^ swk) * 8;
#pragma unroll
    for (int m = 0; m < 4; ++m)
      af[m] = *(const f16x8*)&As[cur][(wr * 64 + m * 16 + l15) * 32 + rpos];
#pragma unroll
    for (int n = 0; n < 4; ++n)
      bf[n] = *(const f16x8*)&Bs[cur][(wc * 64 + n * 16 + l15) * 32 + rpos];
#pragma unroll
    for (int m = 0; m < 4; ++m)
#pragma unroll
      for (int n = 0; n < 4; ++n)
        acc[m][n] = __builtin_amdgcn_mfma_f32_16x16x32_f16(af[m], bf[n], acc[m][n], 0, 0, 0);
    __syncthreads();  // drains vmcnt(0): stage(kt+1) landed; reads of buf cur done
  }
#pragma unroll
  for (int n = 0; n < 4; ++n) {
    int col = col0 + wc * 64 + n * 16 + l15;
    float bv = bias[col];
#pragma unroll
    for (int m = 0; m < 4; ++m) {
      int rowb = row0 + wr * 64 + m * 16 + kb * 4;
#pragma unroll
      for (int r = 0; r < 4; ++r) {
        float v = acc[m][n][r] + bv;
        if (OUT == 2) v = gelu_f(v);
        if (OUT == 3) v += (float)hres[(size_t)(rowb + r) * N + col];
        ((_Float16*)Cv)[(size_t)(rowb + r) * N + col] = (_Float16)v;
      }
    }
  }
}

// ---------------- V transpose per head: qkv v-cols -> vt [b*12+h][64][512] --
__global__ __launch_bounds__(256) void vtrans_kernel(
    const _Float16* __restrict__ v, int RS, _Float16* __restrict__ vt) {
  __shared__ _Float16 T[64][72];
  int s0 = blockIdx.x * 64;
  int bh = blockIdx.y;
  int b = bh / NH_, h = bh % NH_;
  int tid = threadIdx.x;
#pragma unroll
  for (int i = 0; i < 2; ++i) {
    int chunk = tid + i * 256;
    int s = chunk >> 3, dc = (chunk & 7) * 8;
    *(f16x8*)&T[s][dc] = *(const f16x8*)&v[(size_t)(b * S_ + s0 + s) * RS + h * DH_ + dc];
  }
  __syncthreads();
#pragma unroll
  for (int i = 0; i < 2; ++i) {
    int chunk = tid + i * 256;
    int d = chunk >> 3, sc = (chunk & 7) * 8;
    f16x8 o;
#pragma unroll
    for (int j = 0; j < 8; ++j) o[j] = T[sc + j][d];
    *(f16x8*)&vt[(size_t)(bh * DH_ + d) * S_ + s0 + sc] = o;
  }
}

// ---------------- fused flash attention, f16 MFMA ---------------------------
__global__ __launch_bounds__(256) void flash_attn_kernel(
    const _Float16* __restrict__ q, const _Float16* __restrict__ k,
    const _Float16* __restrict__ vt, int RS, const int* __restrict__ mask,
    _Float16* __restrict__ ctx) {
  __shared__ _Float16 Ks[128 * 72];
  __shared__ _Float16 Vs[64 * 136];
  __shared__ _Float16 Ps[4][16 * 136];
  __shared__ float biasz[S_];
  int qt = blockIdx.x, h = blockIdx.y, b = blockIdx.z;
  int tid = threadIdx.x, lane = tid & 63, w = tid >> 6;
  int l15 = lane & 15, kb = lane >> 4;
  const float C = 0.125f * 1.44269504088896f;

  for (int i = tid; i < S_; i += 256)
    biasz[i] = (1.0f - (float)mask[b * S_ + i]) * (-1e9f * C);

  int qrow = b * S_ + qt * 64 + w * 16 + l15;
  f16x8 qf[2];
  qf[0] = *(const f16x8*)&q[(size_t)qrow * RS + h * DH_ + kb * 8];
  qf[1] = *(const f16x8*)&q[(size_t)qrow * RS + h * DH_ + 32 + kb * 8];

  auto loadKV = [&](int kt, f16x8* rk, f16x8* rv) {
#pragma unroll
    for (int i = 0; i < 4; ++i) {
      int idx = tid + i * 256;
      int r = idx >> 3, c = idx & 7;
      rk[i] = *(const f16x8*)&k[(size_t)(b * S_ + kt * 128 + r) * RS + h * DH_ + c * 8];
      int d = idx >> 4, c2 = idx & 15;
      rv[i] = *(const f16x8*)&vt[(size_t)((b * NH_ + h) * DH_ + d) * S_ + kt * 128 + c2 * 8];
    }
  };

  float m_run[4], l_run[4];
  f32x4 o[4] = {};
#pragma unroll
  for (int r = 0; r < 4; ++r) { m_run[r] = -1e30f; l_run[r] = 0.f; }

  f16x8 rk[4], rv[4];
  loadKV(0, rk, rv);
  for (int kt = 0; kt < 4; ++kt) {
    __syncthreads();
#pragma unroll
    for (int i = 0; i < 4; ++i) {
      int idx = tid + i * 256;
      int r = idx >> 3, c = idx & 7;
      *(f16x8*)&Ks[r * 72 + c * 8] = rk[i];
      int d = idx >> 4, c2 = idx & 15;
      *(f16x8*)&Vs[d * 136 + c2 * 8] = rv[i];
    }
    __syncthreads();
    if (kt < 3) loadKV(kt + 1, rk, rv);
    f32x4 s[8];
#pragma unroll
    for (int nf = 0; nf < 8; ++nf) {
      f16x8 b0 = *(const f16x8*)&Ks[(nf * 16 + l15) * 72 + kb * 8];
      f16x8 b1 = *(const f16x8*)&Ks[(nf * 16 + l15) * 72 + 32 + kb * 8];
      f32x4 z = {};
      z = __builtin_amdgcn_mfma_f32_16x16x32_f16(qf[0], b0, z, 0, 0, 0);
      z = __builtin_amdgcn_mfma_f32_16x16x32_f16(qf[1], b1, z, 0, 0, 0);
      s[nf] = z;
    }
    float zb[8];
#pragma unroll
    for (int nf = 0; nf < 8; ++nf) zb[nf] = biasz[kt * 128 + nf * 16 + l15];
    float pw[8][4];
    float corr[4];
#pragma unroll
    for (int r = 0; r < 4; ++r) {
      float mx = -1e30f;
#pragma unroll
      for (int nf = 0; nf < 8; ++nf) mx = fmaxf(mx, s[nf][r] * C + zb[nf]);
#pragma unroll
      for (int d = 1; d < 16; d <<= 1) mx = fmaxf(mx, __shfl_xor(mx, d));
      float mnew = fmaxf(m_run[r], mx);
      float cr = exp2f(m_run[r] - mnew);
      m_run[r] = mnew;
      corr[r] = cr;
      float sum = 0.f;
#pragma unroll
      for (int nf = 0; nf < 8; ++nf) {
        float pv = exp2f(s[nf][r] * C + zb[nf] - mnew);
        pw[nf][r] = pv;
        sum += pv;
      }
#pragma unroll
      for (int d = 1; d < 16; d <<= 1) sum += __shfl_xor(sum, d);
      l_run[r] = l_run[r] * cr + sum;
    }
#pragma unroll
    for (int nf2 = 0; nf2 < 4; ++nf2)
#pragma unroll
      for (int r = 0; r < 4; ++r) o[nf2][r] *= corr[r];
#pragma unroll
    for (int nf = 0; nf < 8; ++nf)
#pragma unroll
      for (int r = 0; r < 4; ++r)
        Ps[w][(kb * 4 + r) * 136 + nf * 16 + l15] = (_Float16)pw[nf][r];
#pragma unroll
    for (int ks = 0; ks < 4; ++ks) {
      f16x8 pa = *(const f16x8*)&Ps[w][l15 * 136 + ks * 32 + kb * 8];
#pragma unroll
      for (int nf2 = 0; nf2 < 4; ++nf2) {
        f16x8 vb2 = *(const f16x8*)&Vs[(nf2 * 16 + l15) * 136 + ks * 32 + kb * 8];
        o[nf2] = __builtin_amdgcn_mfma_f32_16x16x32_f16(pa, vb2, o[nf2], 0, 0, 0);
      }
    }
  }
  float inv[4];
#pragma unroll
  for (int r = 0; r < 4; ++r) inv[r] = 1.0f / fmaxf(l_run[r], 1e-37f);
#pragma unroll
  for (int nf2 = 0; nf2 < 4; ++nf2)
#pragma unroll
    for (int r = 0; r < 4; ++r) {
      int row = b * S_ + qt * 64 + w * 16 + kb * 4 + r;
      ctx[(size_t)row * H_ + h * DH_ + nf2 * 16 + l15] = (_Float16)(o[nf2][r] * inv[r]);
    }
}

// ---------------- valid-token compaction ----------------
__global__ void compact_idx_kernel(const int* __restrict__ valid, int* __restrict__ dest) {
  int b = threadIdx.x;
  if (b >= B_) return;
  int cnt = 0;
  for (int s = 0; s < S_; ++s) {
    int vv = valid[b * S_ + s];
    dest[b * S_ + s] = vv ? cnt : -1;
    cnt += vv;
  }
}

// reads f16 residual stream, writes f32 compact
__global__ __launch_bounds__(192) void scatter_kernel(
    const _Float16* __restrict__ hb, const int* __restrict__ dest,
    float* __restrict__ compact) {
  int tok = blockIdx.x;
  int d = dest[tok];
  if (d < 0) return;
  int b = tok >> 9;
  int j = threadIdx.x * 4;
  f16x4 v = *(const f16x4*)&hb[(size_t)tok * H_ + j];
  float4 o = {(float)v[0], (float)v[1], (float)v[2], (float)v[3]};
  *(float4*)&compact[((size_t)(b * S_ + d)) * H_ + j] = o;
}

// ---------------- classifier + softmax: one wave per token ----------------
__global__ __launch_bounds__(256) void cls_kernel(
    const float* __restrict__ x, const float* __restrict__ W,
    const float* __restrict__ bias2, float* __restrict__ out) {
  int lane = threadIdx.x & 63, wv = threadIdx.x >> 6;
  int tok = blockIdx.x * 4 + wv;
  float acc[NL_] = {};
  for (int hh = lane; hh < H_; hh += 64) {
    float xv = x[(size_t)tok * H_ + hh];
#pragma unroll
    for (int n = 0; n < NL_; ++n) acc[n] = fmaf(xv, W[hh * NL_ + n], acc[n]);
  }
#pragma unroll
  for (int n = 0; n < NL_; ++n) {
#pragma unroll
    for (int off = 32; off; off >>= 1) acc[n] += __shfl_down(acc[n], off);
  }
  if (lane == 0) {
    float vls[NL_], mx = -1e30f;
#pragma unroll
    for (int n = 0; n < NL_; ++n) {
      vls[n] = acc[n] + bias2[n];
      mx = fmaxf(mx, vls[n]);
    }
    float s = 0.f;
#pragma unroll
    for (int n = 0; n < NL_; ++n) {
      vls[n] = expf(vls[n] - mx);
      s += vls[n];
    }
    float inv = 1.0f / s;
#pragma unroll
    for (int n = 0; n < NL_; ++n) out[(size_t)tok * NL_ + n] = vls[n] * inv;
  }
}

extern "C" void kernel_launch(void* const* d_in, const int* in_sizes, int n_in,
                              void* d_out, int out_size, void* d_ws, size_t ws_size,
                              hipStream_t stream) {
  const int* wid = (const int*)d_in[0];
  const int* mask = (const int*)d_in[1];
  const int* tpid = (const int*)d_in[2];
  const int* valid = (const int*)d_in[3];
  const float* we = (const float*)d_in[4];
  const float* pe = (const float*)d_in[5];
  const float* te = (const float*)d_in[6];
  const float* eg = (const float*)d_in[7];
  const float* eb = (const float*)d_in[8];
  const float* Wq = (const float*)d_in[9];
  const float* bq = (const float*)d_in[10];
  const float* Wk = (const float*)d_in[11];
  const float* bk = (const float*)d_in[12];
  const float* Wv = (const float*)d_in[13];
  const float* bv = (const float*)d_in[14];
  const float* Wo = (const float*)d_in[15];
  const float* bo = (const float*)d_in[16];
  const float* g1 = (const float*)d_in[17];
  const float* gb1 = (const float*)d_in[18];
  const float* W1 = (const float*)d_in[19];
  const float* bf1 = (const float*)d_in[20];
  const float* W2 = (const float*)d_in[21];
  const float* bf2 = (const float*)d_in[22];
  const float* g2 = (const float*)d_in[23];
  const float* gb2 = (const float*)d_in[24];
  const float* cW = (const float*)d_in[25];
  const float* cb = (const float*)d_in[26];
  float* out = (float*)d_out;

  const size_t TOK = (size_t)B_ * S_;  // 8192
  char* ws = (char*)d_ws;
  _Float16* hb = (_Float16*)(ws + 25165824);          // 12,582,912 B (residual stream)
  _Float16* t1h = (_Float16*)(ws + 37748736);         // 12,582,912 B (x = delta+res, f16)
  char* un1 = ws + 62914560;                          // 50,331,648 B union
  _Float16* qkv = (_Float16*)un1;                     // [8192][2304] = 37,748,736 B
  _Float16* vt = (_Float16*)(un1 + 37748736);         // 12,582,912 B
  _Float16* ffh = (_Float16*)un1;                     // overlays qkv/vt after attn
  float* compactf = (float*)un1;                      // reused after layers (25MB)
  _Float16* ctx = (_Float16*)(ws + 113246208);        // 12,582,912 B
  char* wbuf = ws + 125829120;                        // 14,155,776 B
  _Float16* wqT = (_Float16*)wbuf;                    // [2304][768] fused (q,k,v rows)
  _Float16* wkT = (_Float16*)(wbuf + 1179648);
  _Float16* wvT = (_Float16*)(wbuf + 2359296);
  _Float16* woT = (_Float16*)(wbuf + 3538944);
  _Float16* w1T = (_Float16*)(wbuf + 4718592);
  _Float16* w2T = (_Float16*)(wbuf + 9437184);
  int* dest = (int*)(ws + 139984896);                 // 32,768 B
  float* qkvb = (float*)(ws + 140017664);             // 9,216 B

  dim3 blk(256);
  dim3 blk192(192);
  embed_ln_kernel<<<dim3((unsigned)TOK), blk, 0, stream>>>(wid, tpid, we, pe, te, eg, eb, hb);

  dim3 gQKV(QKV_ / 128, TOK / 128);  // (18, 64) = 1152 blocks
  dim3 gH(H_ / 128, TOK / 128);      // (6, 64)  = 384 blocks
  dim3 gF(FF_ / 128, TOK / 128);     // (24, 64) = 1536 blocks
  for (int l = 0; l < L_; ++l) {
    convert_weights_kernel<<<dim3(1729), blk, 0, stream>>>(
        Wq + (size_t)l * H_ * H_, Wk + (size_t)l * H_ * H_,
        Wv + (size_t)l * H_ * H_, Wo + (size_t)l * H_ * H_,
        W1 + (size_t)l * H_ * FF_, W2 + (size_t)l * FF_ * H_,
        wqT, wkT, wvT, woT, w1T, w2T,
        bq + l * H_, bk + l * H_, bv + l * H_, qkvb);
    gemm_f16<1><<<gQKV, blk, 0, stream>>>(hb, wqT, qkvb, qkv, (int)TOK, QKV_, H_, nullptr);
    vtrans_kernel<<<dim3(S_ / 64, B_ * NH_), blk, 0, stream>>>(qkv + 2 * H_, QKV_, vt);
    flash_attn_kernel<<<dim3(S_ / 64, NH_, B_), blk, 0, stream>>>(
        qkv, qkv + H_, vt, QKV_, mask, ctx);
    // x = ctx @ Wo + bo + hb  (f16)
    gemm_f16<3><<<gH, blk, 0, stream>>>(ctx, woT, bo + l * H_, t1h, (int)TOK, H_, H_, hb);
    ln_f16_kernel<<<dim3((unsigned)TOK), blk192, 0, stream>>>(t1h, g1 + l * H_, gb1 + l * H_, hb);
    gemm_f16<2><<<gF, blk, 0, stream>>>(hb, w1T, bf1 + l * FF_, ffh, (int)TOK, FF_, H_, nullptr);
    // x = ffh @ W2 + b2 + hb  (f16)
    gemm_f16<3><<<gH, blk, 0, stream>>>(ffh, w2T, bf2 + l * H_, t1h, (int)TOK, H_, FF_, hb);
    ln_f16_kernel<<<dim3((unsigned)TOK), blk192, 0, stream>>>(t1h, g2 + l * H_, gb2 + l * H_, hb);
  }

  compact_idx_kernel<<<1, 64, 0, stream>>>(valid, dest);
  hipMemsetAsync(compactf, 0, TOK * H_ * sizeof(float), stream);
  scatter_kernel<<<dim3((unsigned)TOK), blk192, 0, stream>>>(hb, dest, compactf);
  cls_kernel<<<dim3((unsigned)(TOK / 4)), blk, 0, stream>>>(compactf, cW, cb, out);
}

// Round 9
// 3430.906 us; speedup vs baseline: 1.1250x; 1.0670x over previous
//
#include <hip/hip_runtime.h>
#include <cstdint>
#include <cstddef>

#define B_ 16
#define S_ 512
#define H_ 768
#define L_ 12
#define NH_ 12
#define DH_ 64
#define FF_ 3072
#define NL_ 9
#define QKV_ 2304

typedef _Float16 f16x8 __attribute__((ext_vector_type(8)));
typedef _Float16 f16x4 __attribute__((ext_vector_type(4)));
typedef float f32x4 __attribute__((ext_vector_type(4)));

// ---------------- async global->LDS (16B per lane, wave-uniform LDS base) ---
__device__ __forceinline__ void load_lds16(const void* g, void* l) {
  __builtin_amdgcn_global_load_lds(
      (const __attribute__((address_space(1))) unsigned int*)g,
      (__attribute__((address_space(3))) unsigned int*)l, 16, 0, 0);
}

// ---------------- block reduction helpers ----------------
__device__ __forceinline__ float block_sum256(float v, float* red) {
#pragma unroll
  for (int off = 32; off; off >>= 1) v += __shfl_down(v, off);
  __syncthreads();
  if ((threadIdx.x & 63) == 0) red[threadIdx.x >> 6] = v;
  __syncthreads();
  return red[0] + red[1] + red[2] + red[3];
}

// 192-thread (3-wave) block sum
__device__ __forceinline__ float block_sum192(float v, float* red) {
#pragma unroll
  for (int off = 32; off; off >>= 1) v += __shfl_down(v, off);
  __syncthreads();
  if ((threadIdx.x & 63) == 0) red[threadIdx.x >> 6] = v;
  __syncthreads();
  return red[0] + red[1] + red[2];
}

// Fast exact-GELU: erf via Abramowitz-Stegun 7.1.26 (|err| < 1.5e-7).
__device__ __forceinline__ float gelu_f(float x) {
  float au = fabsf(x) * 0.70710678118654752f;
  float t = 1.0f / (1.0f + 0.3275911f * au);
  float p = ((((1.061405429f * t - 1.453152027f) * t + 1.421413741f) * t
              - 0.284496736f) * t + 0.254829592f) * t;
  float e = p * __expf(-au * au);
  float phi = (x >= 0.0f) ? (1.0f - 0.5f * e) : (0.5f * e);
  return x * phi;
}

// ---------------- embeddings + LayerNorm (writes f16 hb) --------------------
__global__ __launch_bounds__(256) void embed_ln_kernel(
    const int* __restrict__ wid, const int* __restrict__ tpid,
    const float* __restrict__ we, const float* __restrict__ pe,
    const float* __restrict__ te, const float* __restrict__ g,
    const float* __restrict__ bb, _Float16* __restrict__ hb) {
  __shared__ float red[4];
  int tok = blockIdx.x;
  int s = tok & (S_ - 1);
  int w = wid[tok], tp = tpid[tok];
  int t = threadIdx.x;
  float x[3];
#pragma unroll
  for (int i = 0; i < 3; ++i) {
    int j = t + i * 256;
    x[i] = we[(size_t)w * H_ + j] + pe[(size_t)s * H_ + j] + te[(size_t)tp * H_ + j];
  }
  float m = block_sum256(x[0] + x[1] + x[2], red) * (1.0f / H_);
  float d0 = x[0] - m, d1 = x[1] - m, d2 = x[2] - m;
  float var = block_sum256(d0 * d0 + d1 * d1 + d2 * d2, red) * (1.0f / H_);
  float rs = rsqrtf(var + 1e-12f);
#pragma unroll
  for (int i = 0; i < 3; ++i) {
    int j = t + i * 256;
    float v = (x[i] - m) * rs * g[j] + bb[j];
    hb[(size_t)tok * H_ + j] = (_Float16)v;
  }
}

// ---------------- pure LayerNorm on f16 x -> f16 hb (192 thr, f16x4) --------
__global__ __launch_bounds__(192) void ln_f16_kernel(
    const _Float16* __restrict__ x, const float* __restrict__ g,
    const float* __restrict__ bb, _Float16* __restrict__ hb) {
  __shared__ float red[3];
  int tok = blockIdx.x;
  int t = threadIdx.x;
  int j = t * 4;
  f16x4 xv = *(const f16x4*)&x[(size_t)tok * H_ + j];
  float v0 = (float)xv[0], v1 = (float)xv[1], v2 = (float)xv[2], v3 = (float)xv[3];
  float m = block_sum192(v0 + v1 + v2 + v3, red) * (1.0f / H_);
  float d0 = v0 - m, d1 = v1 - m, d2 = v2 - m, d3 = v3 - m;
  __syncthreads();  // red reuse
  float var = block_sum192(d0 * d0 + d1 * d1 + d2 * d2 + d3 * d3, red) * (1.0f / H_);
  float rs = rsqrtf(var + 1e-12f);
  float4 gv = *(const float4*)&g[j];
  float4 bv = *(const float4*)&bb[j];
  f16x4 o;
  o[0] = (_Float16)(d0 * rs * gv.x + bv.x);
  o[1] = (_Float16)(d1 * rs * gv.y + bv.y);
  o[2] = (_Float16)(d2 * rs * gv.z + bv.z);
  o[3] = (_Float16)(d3 * rs * gv.w + bv.w);
  *(f16x4*)&hb[(size_t)tok * H_ + j] = o;
}

// ---------------- per-layer weight convert + transpose: f32 [K][N] -> f16 [N][K]
// block 1728 additionally concats qkv bias. 64x64 tiles.
__global__ __launch_bounds__(256) void convert_weights_kernel(
    const float* __restrict__ Wq, const float* __restrict__ Wk,
    const float* __restrict__ Wv, const float* __restrict__ Wo,
    const float* __restrict__ W1, const float* __restrict__ W2,
    _Float16* __restrict__ qT, _Float16* __restrict__ kT,
    _Float16* __restrict__ vT, _Float16* __restrict__ oT,
    _Float16* __restrict__ w1T, _Float16* __restrict__ w2T,
    const float* __restrict__ bq, const float* __restrict__ bk,
    const float* __restrict__ bv, float* __restrict__ qkvb) {
  int id = blockIdx.x;
  int tid = threadIdx.x;
  if (id == 1728) {  // bias concat
    for (int j = tid; j < H_; j += 256) {
      qkvb[j] = bq[j];
      qkvb[H_ + j] = bk[j];
      qkvb[2 * H_ + j] = bv[j];
    }
    return;
  }
  __shared__ float T[64][65];
  const float* src;
  _Float16* dst;
  int K, N, tk, tn;
  if (id < 576) {
    int mat = id / 144, t = id % 144;
    K = 768; N = 768; tk = t / 12; tn = t % 12;
    src = (mat == 0) ? Wq : (mat == 1) ? Wk : (mat == 2) ? Wv : Wo;
    dst = (mat == 0) ? qT : (mat == 1) ? kT : (mat == 2) ? vT : oT;
  } else if (id < 1152) {
    int t = id - 576; K = 768; N = 3072; tk = t / 48; tn = t % 48;
    src = W1; dst = w1T;
  } else {
    int t = id - 1152; K = 3072; N = 768; tk = t / 12; tn = t % 12;
    src = W2; dst = w2T;
  }
  int k0 = tk * 64, n0 = tn * 64;
  {
    int r = tid >> 4, c4 = (tid & 15) * 4;
#pragma unroll
    for (int i = 0; i < 4; ++i) {
      float4 v = *(const float4*)&src[(size_t)(k0 + r + i * 16) * N + n0 + c4];
      T[r + i * 16][c4 + 0] = v.x;
      T[r + i * 16][c4 + 1] = v.y;
      T[r + i * 16][c4 + 2] = v.z;
      T[r + i * 16][c4 + 3] = v.w;
    }
  }
  __syncthreads();
#pragma unroll
  for (int i = 0; i < 2; ++i) {
    int chunk = tid + i * 256;
    int n = chunk >> 3, kc = (chunk & 7) * 8;
    f16x8 o;
#pragma unroll
    for (int j = 0; j < 8; ++j) o[j] = (_Float16)T[kc + j][n];
    *(f16x8*)&dst[(size_t)(n0 + n) * K + k0 + kc] = o;
  }
}

// ---------------- f16 MFMA GEMM, 2-phase dbuf, BK=64, LDS chunk swizzle -----
// C = A[M,K] @ Bt[N,K]^T + bias. 128x128 tile, BK=64 (halves barrier/drain
// count vs BK=32 — the measured 2-phase fixed cost amortizes over 2x MFMA),
// 256 threads (2x2 waves, 64x64/wave). LDS rows are 128B = 8 x 16B chunks;
// logical chunk c of row r stored at position c^(r&7) (linear global_load_lds
// dest + inverse-swizzled source + swizzled read; quarter-wave = 2 lanes per
// 16B slot = free). stage(t+1) issued BEFORE compute(t); ONE barrier/K-step.
// OUT: 1 = f16+bias, 2 = f16+bias+GELU, 3 = f16+bias+residual(hres f16)
template <int OUT>
__global__ __launch_bounds__(256) void gemm_f16(
    const _Float16* __restrict__ A, const _Float16* __restrict__ Bt,
    const float* __restrict__ bias, void* __restrict__ Cv,
    int M, int N, int K, const _Float16* __restrict__ hres) {
  __shared__ _Float16 As[2][128 * 64];
  __shared__ _Float16 Bs[2][128 * 64];
  int tid = threadIdx.x;
  int lane = tid & 63, w = tid >> 6;
  int wr = w >> 1, wc = w & 1;
  int l15 = lane & 15, kb = lane >> 4;
  int swr = l15 & 7;  // read-side swizzle key (row & 7)

  // XCD-chunked swizzle (bijective when nwg % 8 == 0; all our grids are)
  int nwg = gridDim.x * gridDim.y;
  int bid = blockIdx.y * gridDim.x + blockIdx.x;
  int swz = bid;
  if ((nwg & 7) == 0) {
    int cpx = nwg >> 3;
    swz = (bid & 7) * cpx + (bid >> 3);
  }
  int bx = swz % gridDim.x, by = swz / gridDim.x;
  int row0 = by * 128, col0 = bx * 128;

  // staging: wave w covers rows w*32..w*32+31 per operand, 4 issues of 8 rows.
  // lane l -> LDS slot l (linear): row l>>3, position l&7. That slot holds
  // logical chunk (l&7)^(l>>3), so the lane fetches that global chunk.
  int drow = lane >> 3;                 // 0..7 within an 8-row issue
  int schunk = (lane & 7) ^ drow;       // logical 16B chunk to fetch
  const _Float16* gA = A + (size_t)(row0 + w * 32 + drow) * K + schunk * 8;
  const _Float16* gB = Bt + (size_t)(col0 + w * 32 + drow) * K + schunk * 8;

  auto STAGE = [&](int t, int buf) {  // 8 gload_lds per thread per K-tile
    int ko = t * 64;
#pragma unroll
    for (int j = 0; j < 4; ++j) {
      load_lds16(gA + (size_t)(j * 8) * K + ko,
                 (char*)&As[buf][0] + (w * 32 + j * 8) * 128);
      load_lds16(gB + (size_t)(j * 8) * K + ko,
                 (char*)&Bs[buf][0] + (w * 32 + j * 8) * 128);
    }
  };

  f32x4 acc[4][4] = {};
  int nk = K >> 6;  // K in {768, 3072} -> 12, 48

  STAGE(0, 0);
  __syncthreads();

  for (int kt = 0; kt < nk; ++kt) {
    int cur = kt & 1;
    if (kt + 1 < nk) STAGE(kt + 1, cur ^ 1);
#pragma unroll
    for (int ks = 0; ks < 2; ++ks) {  // two 32-k MFMA subtiles per K-tile
      f16x8 af[4], bf[4];
      int rpos = ((ks * 4 + kb) ^ swr) * 8;  // swizzled chunk position
#pragma unroll
      for (int m = 0; m < 4; ++m)
        af[m] = *(const f16x8*)&As[cur][(wr * 64 + m * 16 + l15) * 64 + rpos];
#pragma unroll
      for (int n = 0; n < 4; ++n)
        bf[n] = *(const f16x8*)&Bs[cur][(wc * 64 + n * 16 + l15) * 64 + rpos];
#pragma unroll
      for (int m = 0; m < 4; ++m)
#pragma unroll
        for (int n = 0; n < 4; ++n)
          acc[m][n] = __builtin_amdgcn_mfma_f32_16x16x32_f16(af[m], bf[n], acc[m][n], 0, 0, 0);
    }
    __syncthreads();  // drains vmcnt(0): stage(kt+1) landed; reads of buf cur done
  }
#pragma unroll
  for (int n = 0; n < 4; ++n) {
    int col = col0 + wc * 64 + n * 16 + l15;
    float bv = bias[col];
#pragma unroll
    for (int m = 0; m < 4; ++m) {
      int rowb = row0 + wr * 64 + m * 16 + kb * 4;
#pragma unroll
      for (int r = 0; r < 4; ++r) {
        float v = acc[m][n][r] + bv;
        if (OUT == 2) v = gelu_f(v);
        if (OUT == 3) v += (float)hres[(size_t)(rowb + r) * N + col];
        ((_Float16*)Cv)[(size_t)(rowb + r) * N + col] = (_Float16)v;
      }
    }
  }
}

// ---------------- V transpose per head: qkv v-cols -> vt [b*12+h][64][512] --
__global__ __launch_bounds__(256) void vtrans_kernel(
    const _Float16* __restrict__ v, int RS, _Float16* __restrict__ vt) {
  __shared__ _Float16 T[64][72];
  int s0 = blockIdx.x * 64;
  int bh = blockIdx.y;
  int b = bh / NH_, h = bh % NH_;
  int tid = threadIdx.x;
#pragma unroll
  for (int i = 0; i < 2; ++i) {
    int chunk = tid + i * 256;
    int s = chunk >> 3, dc = (chunk & 7) * 8;
    *(f16x8*)&T[s][dc] = *(const f16x8*)&v[(size_t)(b * S_ + s0 + s) * RS + h * DH_ + dc];
  }
  __syncthreads();
#pragma unroll
  for (int i = 0; i < 2; ++i) {
    int chunk = tid + i * 256;
    int d = chunk >> 3, sc = (chunk & 7) * 8;
    f16x8 o;
#pragma unroll
    for (int j = 0; j < 8; ++j) o[j] = T[sc + j][d];
    *(f16x8*)&vt[(size_t)(bh * DH_ + d) * S_ + s0 + sc] = o;
  }
}

// ---------------- fused flash attention, f16 MFMA ---------------------------
__global__ __launch_bounds__(256) void flash_attn_kernel(
    const _Float16* __restrict__ q, const _Float16* __restrict__ k,
    const _Float16* __restrict__ vt, int RS, const int* __restrict__ mask,
    _Float16* __restrict__ ctx) {
  __shared__ _Float16 Ks[128 * 72];
  __shared__ _Float16 Vs[64 * 136];
  __shared__ _Float16 Ps[4][16 * 136];
  __shared__ float biasz[S_];
  int qt = blockIdx.x, h = blockIdx.y, b = blockIdx.z;
  int tid = threadIdx.x, lane = tid & 63, w = tid >> 6;
  int l15 = lane & 15, kb = lane >> 4;
  const float C = 0.125f * 1.44269504088896f;

  for (int i = tid; i < S_; i += 256)
    biasz[i] = (1.0f - (float)mask[b * S_ + i]) * (-1e9f * C);

  int qrow = b * S_ + qt * 64 + w * 16 + l15;
  f16x8 qf[2];
  qf[0] = *(const f16x8*)&q[(size_t)qrow * RS + h * DH_ + kb * 8];
  qf[1] = *(const f16x8*)&q[(size_t)qrow * RS + h * DH_ + 32 + kb * 8];

  auto loadKV = [&](int kt, f16x8* rk, f16x8* rv) {
#pragma unroll
    for (int i = 0; i < 4; ++i) {
      int idx = tid + i * 256;
      int r = idx >> 3, c = idx & 7;
      rk[i] = *(const f16x8*)&k[(size_t)(b * S_ + kt * 128 + r) * RS + h * DH_ + c * 8];
      int d = idx >> 4, c2 = idx & 15;
      rv[i] = *(const f16x8*)&vt[(size_t)((b * NH_ + h) * DH_ + d) * S_ + kt * 128 + c2 * 8];
    }
  };

  float m_run[4], l_run[4];
  f32x4 o[4] = {};
#pragma unroll
  for (int r = 0; r < 4; ++r) { m_run[r] = -1e30f; l_run[r] = 0.f; }

  f16x8 rk[4], rv[4];
  loadKV(0, rk, rv);
  for (int kt = 0; kt < 4; ++kt) {
    __syncthreads();
#pragma unroll
    for (int i = 0; i < 4; ++i) {
      int idx = tid + i * 256;
      int r = idx >> 3, c = idx & 7;
      *(f16x8*)&Ks[r * 72 + c * 8] = rk[i];
      int d = idx >> 4, c2 = idx & 15;
      *(f16x8*)&Vs[d * 136 + c2 * 8] = rv[i];
    }
    __syncthreads();
    if (kt < 3) loadKV(kt + 1, rk, rv);
    f32x4 s[8];
#pragma unroll
    for (int nf = 0; nf < 8; ++nf) {
      f16x8 b0 = *(const f16x8*)&Ks[(nf * 16 + l15) * 72 + kb * 8];
      f16x8 b1 = *(const f16x8*)&Ks[(nf * 16 + l15) * 72 + 32 + kb * 8];
      f32x4 z = {};
      z = __builtin_amdgcn_mfma_f32_16x16x32_f16(qf[0], b0, z, 0, 0, 0);
      z = __builtin_amdgcn_mfma_f32_16x16x32_f16(qf[1], b1, z, 0, 0, 0);
      s[nf] = z;
    }
    float zb[8];
#pragma unroll
    for (int nf = 0; nf < 8; ++nf) zb[nf] = biasz[kt * 128 + nf * 16 + l15];
    float pw[8][4];
    float corr[4];
#pragma unroll
    for (int r = 0; r < 4; ++r) {
      float mx = -1e30f;
#pragma unroll
      for (int nf = 0; nf < 8; ++nf) mx = fmaxf(mx, s[nf][r] * C + zb[nf]);
#pragma unroll
      for (int d = 1; d < 16; d <<= 1) mx = fmaxf(mx, __shfl_xor(mx, d));
      float mnew = fmaxf(m_run[r], mx);
      float cr = exp2f(m_run[r] - mnew);
      m_run[r] = mnew;
      corr[r] = cr;
      float sum = 0.f;
#pragma unroll
      for (int nf = 0; nf < 8; ++nf) {
        float pv = exp2f(s[nf][r] * C + zb[nf] - mnew);
        pw[nf][r] = pv;
        sum += pv;
      }
#pragma unroll
      for (int d = 1; d < 16; d <<= 1) sum += __shfl_xor(sum, d);
      l_run[r] = l_run[r] * cr + sum;
    }
#pragma unroll
    for (int nf2 = 0; nf2 < 4; ++nf2)
#pragma unroll
      for (int r = 0; r < 4; ++r) o[nf2][r] *= corr[r];
#pragma unroll
    for (int nf = 0; nf < 8; ++nf)
#pragma unroll
      for (int r = 0; r < 4; ++r)
        Ps[w][(kb * 4 + r) * 136 + nf * 16 + l15] = (_Float16)pw[nf][r];
#pragma unroll
    for (int ks = 0; ks < 4; ++ks) {
      f16x8 pa = *(const f16x8*)&Ps[w][l15 * 136 + ks * 32 + kb * 8];
#pragma unroll
      for (int nf2 = 0; nf2 < 4; ++nf2) {
        f16x8 vb2 = *(const f16x8*)&Vs[(nf2 * 16 + l15) * 136 + ks * 32 + kb * 8];
        o[nf2] = __builtin_amdgcn_mfma_f32_16x16x32_f16(pa, vb2, o[nf2], 0, 0, 0);
      }
    }
  }
  float inv[4];
#pragma unroll
  for (int r = 0; r < 4; ++r) inv[r] = 1.0f / fmaxf(l_run[r], 1e-37f);
#pragma unroll
  for (int nf2 = 0; nf2 < 4; ++nf2)
#pragma unroll
    for (int r = 0; r < 4; ++r) {
      int row = b * S_ + qt * 64 + w * 16 + kb * 4 + r;
      ctx[(size_t)row * H_ + h * DH_ + nf2 * 16 + l15] = (_Float16)(o[nf2][r] * inv[r]);
    }
}

// ---------------- valid-token compaction ----------------
__global__ void compact_idx_kernel(const int* __restrict__ valid, int* __restrict__ dest) {
  int b = threadIdx.x;
  if (b >= B_) return;
  int cnt = 0;
  for (int s = 0; s < S_; ++s) {
    int vv = valid[b * S_ + s];
    dest[b * S_ + s] = vv ? cnt : -1;
    cnt += vv;
  }
}

// reads f16 residual stream, writes f32 compact
__global__ __launch_bounds__(192) void scatter_kernel(
    const _Float16* __restrict__ hb, const int* __restrict__ dest,
    float* __restrict__ compact) {
  int tok = blockIdx.x;
  int d = dest[tok];
  if (d < 0) return;
  int b = tok >> 9;
  int j = threadIdx.x * 4;
  f16x4 v = *(const f16x4*)&hb[(size_t)tok * H_ + j];
  float4 o = {(float)v[0], (float)v[1], (float)v[2], (float)v[3]};
  *(float4*)&compact[((size_t)(b * S_ + d)) * H_ + j] = o;
}

// ---------------- classifier + softmax: one wave per token ----------------
__global__ __launch_bounds__(256) void cls_kernel(
    const float* __restrict__ x, const float* __restrict__ W,
    const float* __restrict__ bias2, float* __restrict__ out) {
  int lane = threadIdx.x & 63, wv = threadIdx.x >> 6;
  int tok = blockIdx.x * 4 + wv;
  float acc[NL_] = {};
  for (int hh = lane; hh < H_; hh += 64) {
    float xv = x[(size_t)tok * H_ + hh];
#pragma unroll
    for (int n = 0; n < NL_; ++n) acc[n] = fmaf(xv, W[hh * NL_ + n], acc[n]);
  }
#pragma unroll
  for (int n = 0; n < NL_; ++n) {
#pragma unroll
    for (int off = 32; off; off >>= 1) acc[n] += __shfl_down(acc[n], off);
  }
  if (lane == 0) {
    float vls[NL_], mx = -1e30f;
#pragma unroll
    for (int n = 0; n < NL_; ++n) {
      vls[n] = acc[n] + bias2[n];
      mx = fmaxf(mx, vls[n]);
    }
    float s = 0.f;
#pragma unroll
    for (int n = 0; n < NL_; ++n) {
      vls[n] = expf(vls[n] - mx);
      s += vls[n];
    }
    float inv = 1.0f / s;
#pragma unroll
    for (int n = 0; n < NL_; ++n) out[(size_t)tok * NL_ + n] = vls[n] * inv;
  }
}

extern "C" void kernel_launch(void* const* d_in, const int* in_sizes, int n_in,
                              void* d_out, int out_size, void* d_ws, size_t ws_size,
                              hipStream_t stream) {
  const int* wid = (const int*)d_in[0];
  const int* mask = (const int*)d_in[1];
  const int* tpid = (const int*)d_in[2];
  const int* valid = (const int*)d_in[3];
  const float* we = (const float*)d_in[4];
  const float* pe = (const float*)d_in[5];
  const float* te = (const float*)d_in[6];
  const float* eg = (const float*)d_in[7];
  const float* eb = (const float*)d_in[8];
  const float* Wq = (const float*)d_in[9];
  const float* bq = (const float*)d_in[10];
  const float* Wk = (const float*)d_in[11];
  const float* bk = (const float*)d_in[12];
  const float* Wv = (const float*)d_in[13];
  const float* bv = (const float*)d_in[14];
  const float* Wo = (const float*)d_in[15];
  const float* bo = (const float*)d_in[16];
  const float* g1 = (const float*)d_in[17];
  const float* gb1 = (const float*)d_in[18];
  const float* W1 = (const float*)d_in[19];
  const float* bf1 = (const float*)d_in[20];
  const float* W2 = (const float*)d_in[21];
  const float* bf2 = (const float*)d_in[22];
  const float* g2 = (const float*)d_in[23];
  const float* gb2 = (const float*)d_in[24];
  const float* cW = (const float*)d_in[25];
  const float* cb = (const float*)d_in[26];
  float* out = (float*)d_out;

  const size_t TOK = (size_t)B_ * S_;  // 8192
  char* ws = (char*)d_ws;
  _Float16* hb = (_Float16*)(ws + 25165824);          // 12,582,912 B (residual stream)
  _Float16* t1h = (_Float16*)(ws + 37748736);         // 12,582,912 B (x = delta+res, f16)
  char* un1 = ws + 62914560;                          // 50,331,648 B union
  _Float16* qkv = (_Float16*)un1;                     // [8192][2304] = 37,748,736 B
  _Float16* vt = (_Float16*)(un1 + 37748736);         // 12,582,912 B
  _Float16* ffh = (_Float16*)un1;                     // overlays qkv/vt after attn
  float* compactf = (float*)un1;                      // reused after layers (25MB)
  _Float16* ctx = (_Float16*)(ws + 113246208);        // 12,582,912 B
  char* wbuf = ws + 125829120;                        // 14,155,776 B
  _Float16* wqT = (_Float16*)wbuf;                    // [2304][768] fused (q,k,v rows)
  _Float16* wkT = (_Float16*)(wbuf + 1179648);
  _Float16* wvT = (_Float16*)(wbuf + 2359296);
  _Float16* woT = (_Float16*)(wbuf + 3538944);
  _Float16* w1T = (_Float16*)(wbuf + 4718592);
  _Float16* w2T = (_Float16*)(wbuf + 9437184);
  int* dest = (int*)(ws + 139984896);                 // 32,768 B
  float* qkvb = (float*)(ws + 140017664);             // 9,216 B

  dim3 blk(256);
  dim3 blk192(192);
  embed_ln_kernel<<<dim3((unsigned)TOK), blk, 0, stream>>>(wid, tpid, we, pe, te, eg, eb, hb);

  dim3 gQKV(QKV_ / 128, TOK / 128);  // (18, 64) = 1152 blocks
  dim3 gH(H_ / 128, TOK / 128);      // (6, 64)  = 384 blocks
  dim3 gF(FF_ / 128, TOK / 128);     // (24, 64) = 1536 blocks
  for (int l = 0; l < L_; ++l) {
    convert_weights_kernel<<<dim3(1729), blk, 0, stream>>>(
        Wq + (size_t)l * H_ * H_, Wk + (size_t)l * H_ * H_,
        Wv + (size_t)l * H_ * H_, Wo + (size_t)l * H_ * H_,
        W1 + (size_t)l * H_ * FF_, W2 + (size_t)l * FF_ * H_,
        wqT, wkT, wvT, woT, w1T, w2T,
        bq + l * H_, bk + l * H_, bv + l * H_, qkvb);
    gemm_f16<1><<<gQKV, blk, 0, stream>>>(hb, wqT, qkvb, qkv, (int)TOK, QKV_, H_, nullptr);
    vtrans_kernel<<<dim3(S_ / 64, B_ * NH_), blk, 0, stream>>>(qkv + 2 * H_, QKV_, vt);
    flash_attn_kernel<<<dim3(S_ / 64, NH_, B_), blk, 0, stream>>>(
        qkv, qkv + H_, vt, QKV_, mask, ctx);
    // x = ctx @ Wo + bo + hb  (f16)
    gemm_f16<3><<<gH, blk, 0, stream>>>(ctx, woT, bo + l * H_, t1h, (int)TOK, H_, H_, hb);
    ln_f16_kernel<<<dim3((unsigned)TOK), blk192, 0, stream>>>(t1h, g1 + l * H_, gb1 + l * H_, hb);
    gemm_f16<2><<<gF, blk, 0, stream>>>(hb, w1T, bf1 + l * FF_, ffh, (int)TOK, FF_, H_, nullptr);
    // x = ffh @ W2 + b2 + hb  (f16)
    gemm_f16<3><<<gH, blk, 0, stream>>>(ffh, w2T, bf2 + l * H_, t1h, (int)TOK, H_, FF_, hb);
    ln_f16_kernel<<<dim3((unsigned)TOK), blk192, 0, stream>>>(t1h, g2 + l * H_, gb2 + l * H_, hb);
  }

  compact_idx_kernel<<<1, 64, 0, stream>>>(valid, dest);
  hipMemsetAsync(compactf, 0, TOK * H_ * sizeof(float), stream);
  scatter_kernel<<<dim3((unsigned)TOK), blk192, 0, stream>>>(hb, dest, compactf);
  cls_kernel<<<dim3((unsigned)(TOK / 4)), blk, 0, stream>>>(compactf, cW, cb, out);
}

// Round 10
// 3370.210 us; speedup vs baseline: 1.1453x; 1.0180x over previous
//
#include <hip/hip_runtime.h>
#include <cstdint>
#include <cstddef>

#define B_ 16
#define S_ 512
#define H_ 768
#define L_ 12
#define NH_ 12
#define DH_ 64
#define FF_ 3072
#define NL_ 9
#define QKV_ 2304

typedef _Float16 f16x8 __attribute__((ext_vector_type(8)));
typedef _Float16 f16x4 __attribute__((ext_vector_type(4)));
typedef float f32x4 __attribute__((ext_vector_type(4)));

// ---------------- async global->LDS (16B per lane, wave-uniform LDS base) ---
__device__ __forceinline__ void load_lds16(const void* g, void* l) {
  __builtin_amdgcn_global_load_lds(
      (const __attribute__((address_space(1))) unsigned int*)g,
      (__attribute__((address_space(3))) unsigned int*)l, 16, 0, 0);
}

// ---------------- block reduction helpers ----------------
__device__ __forceinline__ float block_sum256(float v, float* red) {
#pragma unroll
  for (int off = 32; off; off >>= 1) v += __shfl_down(v, off);
  __syncthreads();
  if ((threadIdx.x & 63) == 0) red[threadIdx.x >> 6] = v;
  __syncthreads();
  return red[0] + red[1] + red[2] + red[3];
}

// 192-thread (3-wave) block sum
__device__ __forceinline__ float block_sum192(float v, float* red) {
#pragma unroll
  for (int off = 32; off; off >>= 1) v += __shfl_down(v, off);
  __syncthreads();
  if ((threadIdx.x & 63) == 0) red[threadIdx.x >> 6] = v;
  __syncthreads();
  return red[0] + red[1] + red[2];
}

// Fast exact-GELU: erf via Abramowitz-Stegun 7.1.26 (|err| < 1.5e-7).
__device__ __forceinline__ float gelu_f(float x) {
  float au = fabsf(x) * 0.70710678118654752f;
  float t = 1.0f / (1.0f + 0.3275911f * au);
  float p = ((((1.061405429f * t - 1.453152027f) * t + 1.421413741f) * t
              - 0.284496736f) * t + 0.254829592f) * t;
  float e = p * __expf(-au * au);
  float phi = (x >= 0.0f) ? (1.0f - 0.5f * e) : (0.5f * e);
  return x * phi;
}

// ---------------- embeddings + LayerNorm (writes f16 hb) --------------------
__global__ __launch_bounds__(256) void embed_ln_kernel(
    const int* __restrict__ wid, const int* __restrict__ tpid,
    const float* __restrict__ we, const float* __restrict__ pe,
    const float* __restrict__ te, const float* __restrict__ g,
    const float* __restrict__ bb, _Float16* __restrict__ hb) {
  __shared__ float red[4];
  int tok = blockIdx.x;
  int s = tok & (S_ - 1);
  int w = wid[tok], tp = tpid[tok];
  int t = threadIdx.x;
  float x[3];
#pragma unroll
  for (int i = 0; i < 3; ++i) {
    int j = t + i * 256;
    x[i] = we[(size_t)w * H_ + j] + pe[(size_t)s * H_ + j] + te[(size_t)tp * H_ + j];
  }
  float m = block_sum256(x[0] + x[1] + x[2], red) * (1.0f / H_);
  float d0 = x[0] - m, d1 = x[1] - m, d2 = x[2] - m;
  float var = block_sum256(d0 * d0 + d1 * d1 + d2 * d2, red) * (1.0f / H_);
  float rs = rsqrtf(var + 1e-12f);
#pragma unroll
  for (int i = 0; i < 3; ++i) {
    int j = t + i * 256;
    float v = (x[i] - m) * rs * g[j] + bb[j];
    hb[(size_t)tok * H_ + j] = (_Float16)v;
  }
}

// ---------------- pure LayerNorm on f16 x -> f16 hb (192 thr, f16x4) --------
__global__ __launch_bounds__(192) void ln_f16_kernel(
    const _Float16* __restrict__ x, const float* __restrict__ g,
    const float* __restrict__ bb, _Float16* __restrict__ hb) {
  __shared__ float red[3];
  int tok = blockIdx.x;
  int t = threadIdx.x;
  int j = t * 4;
  f16x4 xv = *(const f16x4*)&x[(size_t)tok * H_ + j];
  float v0 = (float)xv[0], v1 = (float)xv[1], v2 = (float)xv[2], v3 = (float)xv[3];
  float m = block_sum192(v0 + v1 + v2 + v3, red) * (1.0f / H_);
  float d0 = v0 - m, d1 = v1 - m, d2 = v2 - m, d3 = v3 - m;
  __syncthreads();  // red reuse
  float var = block_sum192(d0 * d0 + d1 * d1 + d2 * d2 + d3 * d3, red) * (1.0f / H_);
  float rs = rsqrtf(var + 1e-12f);
  float4 gv = *(const float4*)&g[j];
  float4 bv = *(const float4*)&bb[j];
  f16x4 o;
  o[0] = (_Float16)(d0 * rs * gv.x + bv.x);
  o[1] = (_Float16)(d1 * rs * gv.y + bv.y);
  o[2] = (_Float16)(d2 * rs * gv.z + bv.z);
  o[3] = (_Float16)(d3 * rs * gv.w + bv.w);
  *(f16x4*)&hb[(size_t)tok * H_ + j] = o;
}

// ---------------- per-layer weight convert + transpose: f32 [K][N] -> f16 [N][K]
// block 1728 additionally concats qkv bias. 64x64 tiles.
__global__ __launch_bounds__(256) void convert_weights_kernel(
    const float* __restrict__ Wq, const float* __restrict__ Wk,
    const float* __restrict__ Wv, const float* __restrict__ Wo,
    const float* __restrict__ W1, const float* __restrict__ W2,
    _Float16* __restrict__ qT, _Float16* __restrict__ kT,
    _Float16* __restrict__ vT, _Float16* __restrict__ oT,
    _Float16* __restrict__ w1T, _Float16* __restrict__ w2T,
    const float* __restrict__ bq, const float* __restrict__ bk,
    const float* __restrict__ bv, float* __restrict__ qkvb) {
  int id = blockIdx.x;
  int tid = threadIdx.x;
  if (id == 1728) {  // bias concat
    for (int j = tid; j < H_; j += 256) {
      qkvb[j] = bq[j];
      qkvb[H_ + j] = bk[j];
      qkvb[2 * H_ + j] = bv[j];
    }
    return;
  }
  __shared__ float T[64][65];
  const float* src;
  _Float16* dst;
  int K, N, tk, tn;
  if (id < 576) {
    int mat = id / 144, t = id % 144;
    K = 768; N = 768; tk = t / 12; tn = t % 12;
    src = (mat == 0) ? Wq : (mat == 1) ? Wk : (mat == 2) ? Wv : Wo;
    dst = (mat == 0) ? qT : (mat == 1) ? kT : (mat == 2) ? vT : oT;
  } else if (id < 1152) {
    int t = id - 576; K = 768; N = 3072; tk = t / 48; tn = t % 48;
    src = W1; dst = w1T;
  } else {
    int t = id - 1152; K = 3072; N = 768; tk = t / 12; tn = t % 12;
    src = W2; dst = w2T;
  }
  int k0 = tk * 64, n0 = tn * 64;
  {
    int r = tid >> 4, c4 = (tid & 15) * 4;
#pragma unroll
    for (int i = 0; i < 4; ++i) {
      float4 v = *(const float4*)&src[(size_t)(k0 + r + i * 16) * N + n0 + c4];
      T[r + i * 16][c4 + 0] = v.x;
      T[r + i * 16][c4 + 1] = v.y;
      T[r + i * 16][c4 + 2] = v.z;
      T[r + i * 16][c4 + 3] = v.w;
    }
  }
  __syncthreads();
#pragma unroll
  for (int i = 0; i < 2; ++i) {
    int chunk = tid + i * 256;
    int n = chunk >> 3, kc = (chunk & 7) * 8;
    f16x8 o;
#pragma unroll
    for (int j = 0; j < 8; ++j) o[j] = (_Float16)T[kc + j][n];
    *(f16x8*)&dst[(size_t)(n0 + n) * K + k0 + kc] = o;
  }
}

// ---------------- f16 MFMA GEMM, 2-phase dbuf, BM=128, BK=64 (r9, proven) ---
// OUT: 1 = f16+bias, 2 = f16+bias+GELU, 3 = f16+bias+residual(hres f16)
template <int OUT>
__global__ __launch_bounds__(256) void gemm_f16(
    const _Float16* __restrict__ A, const _Float16* __restrict__ Bt,
    const float* __restrict__ bias, void* __restrict__ Cv,
    int M, int N, int K, const _Float16* __restrict__ hres) {
  __shared__ _Float16 As[2][128 * 64];
  __shared__ _Float16 Bs[2][128 * 64];
  int tid = threadIdx.x;
  int lane = tid & 63, w = tid >> 6;
  int wr = w >> 1, wc = w & 1;
  int l15 = lane & 15, kb = lane >> 4;
  int swr = l15 & 7;

  int nwg = gridDim.x * gridDim.y;
  int bid = blockIdx.y * gridDim.x + blockIdx.x;
  int swz = bid;
  if ((nwg & 7) == 0) {
    int cpx = nwg >> 3;
    swz = (bid & 7) * cpx + (bid >> 3);
  }
  int bx = swz % gridDim.x, by = swz / gridDim.x;
  int row0 = by * 128, col0 = bx * 128;

  int drow = lane >> 3;
  int schunk = (lane & 7) ^ drow;
  const _Float16* gA = A + (size_t)(row0 + w * 32 + drow) * K + schunk * 8;
  const _Float16* gB = Bt + (size_t)(col0 + w * 32 + drow) * K + schunk * 8;

  auto STAGE = [&](int t, int buf) {
    int ko = t * 64;
#pragma unroll
    for (int j = 0; j < 4; ++j) {
      load_lds16(gA + (size_t)(j * 8) * K + ko,
                 (char*)&As[buf][0] + (w * 32 + j * 8) * 128);
      load_lds16(gB + (size_t)(j * 8) * K + ko,
                 (char*)&Bs[buf][0] + (w * 32 + j * 8) * 128);
    }
  };

  f32x4 acc[4][4] = {};
  int nk = K >> 6;

  STAGE(0, 0);
  __syncthreads();

  for (int kt = 0; kt < nk; ++kt) {
    int cur = kt & 1;
    if (kt + 1 < nk) STAGE(kt + 1, cur ^ 1);
#pragma unroll
    for (int ks = 0; ks < 2; ++ks) {
      f16x8 af[4], bf[4];
      int rpos = ((ks * 4 + kb) ^ swr) * 8;
#pragma unroll
      for (int m = 0; m < 4; ++m)
        af[m] = *(const f16x8*)&As[cur][(wr * 64 + m * 16 + l15) * 64 + rpos];
#pragma unroll
      for (int n = 0; n < 4; ++n)
        bf[n] = *(const f16x8*)&Bs[cur][(wc * 64 + n * 16 + l15) * 64 + rpos];
#pragma unroll
      for (int m = 0; m < 4; ++m)
#pragma unroll
        for (int n = 0; n < 4; ++n)
          acc[m][n] = __builtin_amdgcn_mfma_f32_16x16x32_f16(af[m], bf[n], acc[m][n], 0, 0, 0);
    }
    __syncthreads();
  }
#pragma unroll
  for (int n = 0; n < 4; ++n) {
    int col = col0 + wc * 64 + n * 16 + l15;
    float bv = bias[col];
#pragma unroll
    for (int m = 0; m < 4; ++m) {
      int rowb = row0 + wr * 64 + m * 16 + kb * 4;
#pragma unroll
      for (int r = 0; r < 4; ++r) {
        float v = acc[m][n][r] + bv;
        if (OUT == 2) v = gelu_f(v);
        if (OUT == 3) v += (float)hres[(size_t)(rowb + r) * N + col];
        ((_Float16*)Cv)[(size_t)(rowb + r) * N + col] = (_Float16)v;
      }
    }
  }
}

// ---------------- f16 MFMA GEMM, BM=64 x BN=128, BK=64, 128 threads ---------
// Same 2-phase schedule/swizzle as gemm_f16; 48KB LDS -> 3 blocks/CU (768
// co-resident). Rebalances the N=768 GEMMs (grid 768 = exactly 1 round) and
// QKV (2304 = 3 exact rounds, was 2.25 at BM=128). Wave w owns cols w*64.
template <int OUT>
__global__ __launch_bounds__(128) void gemm64(
    const _Float16* __restrict__ A, const _Float16* __restrict__ Bt,
    const float* __restrict__ bias, void* __restrict__ Cv,
    int M, int N, int K, const _Float16* __restrict__ hres) {
  __shared__ _Float16 As[2][64 * 64];
  __shared__ _Float16 Bs[2][128 * 64];
  int tid = threadIdx.x;
  int lane = tid & 63, w = tid >> 6;  // w in {0,1}
  int l15 = lane & 15, kb = lane >> 4;
  int swr = l15 & 7;

  int nwg = gridDim.x * gridDim.y;
  int bid = blockIdx.y * gridDim.x + blockIdx.x;
  int swz = bid;
  if ((nwg & 7) == 0) {
    int cpx = nwg >> 3;
    swz = (bid & 7) * cpx + (bid >> 3);
  }
  int bx = swz % gridDim.x, by = swz / gridDim.x;
  int row0 = by * 64, col0 = bx * 128;

  int drow = lane >> 3;
  int schunk = (lane & 7) ^ drow;
  const _Float16* gA = A + (size_t)(row0 + w * 32 + drow) * K + schunk * 8;
  const _Float16* gB = Bt + (size_t)(col0 + w * 64 + drow) * K + schunk * 8;

  auto STAGE = [&](int t, int buf) {  // A: 4 issues of 8 rows; B: 8 issues
    int ko = t * 64;
#pragma unroll
    for (int j = 0; j < 4; ++j)
      load_lds16(gA + (size_t)(j * 8) * K + ko,
                 (char*)&As[buf][0] + (w * 32 + j * 8) * 128);
#pragma unroll
    for (int j = 0; j < 8; ++j)
      load_lds16(gB + (size_t)(j * 8) * K + ko,
                 (char*)&Bs[buf][0] + (w * 64 + j * 8) * 128);
  };

  f32x4 acc[4][4] = {};
  int nk = K >> 6;

  STAGE(0, 0);
  __syncthreads();

  for (int kt = 0; kt < nk; ++kt) {
    int cur = kt & 1;
    if (kt + 1 < nk) STAGE(kt + 1, cur ^ 1);
#pragma unroll
    for (int ks = 0; ks < 2; ++ks) {
      f16x8 af[4], bf[4];
      int rpos = ((ks * 4 + kb) ^ swr) * 8;
#pragma unroll
      for (int m = 0; m < 4; ++m)
        af[m] = *(const f16x8*)&As[cur][(m * 16 + l15) * 64 + rpos];
#pragma unroll
      for (int n = 0; n < 4; ++n)
        bf[n] = *(const f16x8*)&Bs[cur][(w * 64 + n * 16 + l15) * 64 + rpos];
#pragma unroll
      for (int m = 0; m < 4; ++m)
#pragma unroll
        for (int n = 0; n < 4; ++n)
          acc[m][n] = __builtin_amdgcn_mfma_f32_16x16x32_f16(af[m], bf[n], acc[m][n], 0, 0, 0);
    }
    __syncthreads();
  }
#pragma unroll
  for (int n = 0; n < 4; ++n) {
    int col = col0 + w * 64 + n * 16 + l15;
    float bv = bias[col];
#pragma unroll
    for (int m = 0; m < 4; ++m) {
      int rowb = row0 + m * 16 + kb * 4;
#pragma unroll
      for (int r = 0; r < 4; ++r) {
        float v = acc[m][n][r] + bv;
        if (OUT == 2) v = gelu_f(v);
        if (OUT == 3) v += (float)hres[(size_t)(rowb + r) * N + col];
        ((_Float16*)Cv)[(size_t)(rowb + r) * N + col] = (_Float16)v;
      }
    }
  }
}

// ---------------- V transpose per head: qkv v-cols -> vt [b*12+h][64][512] --
__global__ __launch_bounds__(256) void vtrans_kernel(
    const _Float16* __restrict__ v, int RS, _Float16* __restrict__ vt) {
  __shared__ _Float16 T[64][72];
  int s0 = blockIdx.x * 64;
  int bh = blockIdx.y;
  int b = bh / NH_, h = bh % NH_;
  int tid = threadIdx.x;
#pragma unroll
  for (int i = 0; i < 2; ++i) {
    int chunk = tid + i * 256;
    int s = chunk >> 3, dc = (chunk & 7) * 8;
    *(f16x8*)&T[s][dc] = *(const f16x8*)&v[(size_t)(b * S_ + s0 + s) * RS + h * DH_ + dc];
  }
  __syncthreads();
#pragma unroll
  for (int i = 0; i < 2; ++i) {
    int chunk = tid + i * 256;
    int d = chunk >> 3, sc = (chunk & 7) * 8;
    f16x8 o;
#pragma unroll
    for (int j = 0; j < 8; ++j) o[j] = T[sc + j][d];
    *(f16x8*)&vt[(size_t)(bh * DH_ + d) * S_ + s0 + sc] = o;
  }
}

// ---------------- fused flash attention, f16 MFMA ---------------------------
__global__ __launch_bounds__(256) void flash_attn_kernel(
    const _Float16* __restrict__ q, const _Float16* __restrict__ k,
    const _Float16* __restrict__ vt, int RS, const int* __restrict__ mask,
    _Float16* __restrict__ ctx) {
  __shared__ _Float16 Ks[128 * 72];
  __shared__ _Float16 Vs[64 * 136];
  __shared__ _Float16 Ps[4][16 * 136];
  __shared__ float biasz[S_];
  int qt = blockIdx.x, h = blockIdx.y, b = blockIdx.z;
  int tid = threadIdx.x, lane = tid & 63, w = tid >> 6;
  int l15 = lane & 15, kb = lane >> 4;
  const float C = 0.125f * 1.44269504088896f;

  for (int i = tid; i < S_; i += 256)
    biasz[i] = (1.0f - (float)mask[b * S_ + i]) * (-1e9f * C);

  int qrow = b * S_ + qt * 64 + w * 16 + l15;
  f16x8 qf[2];
  qf[0] = *(const f16x8*)&q[(size_t)qrow * RS + h * DH_ + kb * 8];
  qf[1] = *(const f16x8*)&q[(size_t)qrow * RS + h * DH_ + 32 + kb * 8];

  auto loadKV = [&](int kt, f16x8* rk, f16x8* rv) {
#pragma unroll
    for (int i = 0; i < 4; ++i) {
      int idx = tid + i * 256;
      int r = idx >> 3, c = idx & 7;
      rk[i] = *(const f16x8*)&k[(size_t)(b * S_ + kt * 128 + r) * RS + h * DH_ + c * 8];
      int d = idx >> 4, c2 = idx & 15;
      rv[i] = *(const f16x8*)&vt[(size_t)((b * NH_ + h) * DH_ + d) * S_ + kt * 128 + c2 * 8];
    }
  };

  float m_run[4], l_run[4];
  f32x4 o[4] = {};
#pragma unroll
  for (int r = 0; r < 4; ++r) { m_run[r] = -1e30f; l_run[r] = 0.f; }

  f16x8 rk[4], rv[4];
  loadKV(0, rk, rv);
  for (int kt = 0; kt < 4; ++kt) {
    __syncthreads();
#pragma unroll
    for (int i = 0; i < 4; ++i) {
      int idx = tid + i * 256;
      int r = idx >> 3, c = idx & 7;
      *(f16x8*)&Ks[r * 72 + c * 8] = rk[i];
      int d = idx >> 4, c2 = idx & 15;
      *(f16x8*)&Vs[d * 136 + c2 * 8] = rv[i];
    }
    __syncthreads();
    if (kt < 3) loadKV(kt + 1, rk, rv);
    f32x4 s[8];
#pragma unroll
    for (int nf = 0; nf < 8; ++nf) {
      f16x8 b0 = *(const f16x8*)&Ks[(nf * 16 + l15) * 72 + kb * 8];
      f16x8 b1 = *(const f16x8*)&Ks[(nf * 16 + l15) * 72 + 32 + kb * 8];
      f32x4 z = {};
      z = __builtin_amdgcn_mfma_f32_16x16x32_f16(qf[0], b0, z, 0, 0, 0);
      z = __builtin_amdgcn_mfma_f32_16x16x32_f16(qf[1], b1, z, 0, 0, 0);
      s[nf] = z;
    }
    float zb[8];
#pragma unroll
    for (int nf = 0; nf < 8; ++nf) zb[nf] = biasz[kt * 128 + nf * 16 + l15];
    float pw[8][4];
    float corr[4];
#pragma unroll
    for (int r = 0; r < 4; ++r) {
      float mx = -1e30f;
#pragma unroll
      for (int nf = 0; nf < 8; ++nf) mx = fmaxf(mx, s[nf][r] * C + zb[nf]);
#pragma unroll
      for (int d = 1; d < 16; d <<= 1) mx = fmaxf(mx, __shfl_xor(mx, d));
      float mnew = fmaxf(m_run[r], mx);
      float cr = exp2f(m_run[r] - mnew);
      m_run[r] = mnew;
      corr[r] = cr;
      float sum = 0.f;
#pragma unroll
      for (int nf = 0; nf < 8; ++nf) {
        float pv = exp2f(s[nf][r] * C + zb[nf] - mnew);
        pw[nf][r] = pv;
        sum += pv;
      }
#pragma unroll
      for (int d = 1; d < 16; d <<= 1) sum += __shfl_xor(sum, d);
      l_run[r] = l_run[r] * cr + sum;
    }
#pragma unroll
    for (int nf2 = 0; nf2 < 4; ++nf2)
#pragma unroll
      for (int r = 0; r < 4; ++r) o[nf2][r] *= corr[r];
#pragma unroll
    for (int nf = 0; nf < 8; ++nf)
#pragma unroll
      for (int r = 0; r < 4; ++r)
        Ps[w][(kb * 4 + r) * 136 + nf * 16 + l15] = (_Float16)pw[nf][r];
#pragma unroll
    for (int ks = 0; ks < 4; ++ks) {
      f16x8 pa = *(const f16x8*)&Ps[w][l15 * 136 + ks * 32 + kb * 8];
#pragma unroll
      for (int nf2 = 0; nf2 < 4; ++nf2) {
        f16x8 vb2 = *(const f16x8*)&Vs[(nf2 * 16 + l15) * 136 + ks * 32 + kb * 8];
        o[nf2] = __builtin_amdgcn_mfma_f32_16x16x32_f16(pa, vb2, o[nf2], 0, 0, 0);
      }
    }
  }
  float inv[4];
#pragma unroll
  for (int r = 0; r < 4; ++r) inv[r] = 1.0f / fmaxf(l_run[r], 1e-37f);
#pragma unroll
  for (int nf2 = 0; nf2 < 4; ++nf2)
#pragma unroll
    for (int r = 0; r < 4; ++r) {
      int row = b * S_ + qt * 64 + w * 16 + kb * 4 + r;
      ctx[(size_t)row * H_ + h * DH_ + nf2 * 16 + l15] = (_Float16)(o[nf2][r] * inv[r]);
    }
}

// ---------------- valid-token compaction ----------------
__global__ void compact_idx_kernel(const int* __restrict__ valid, int* __restrict__ dest) {
  int b = threadIdx.x;
  if (b >= B_) return;
  int cnt = 0;
  for (int s = 0; s < S_; ++s) {
    int vv = valid[b * S_ + s];
    dest[b * S_ + s] = vv ? cnt : -1;
    cnt += vv;
  }
}

// reads f16 residual stream, writes f32 compact
__global__ __launch_bounds__(192) void scatter_kernel(
    const _Float16* __restrict__ hb, const int* __restrict__ dest,
    float* __restrict__ compact) {
  int tok = blockIdx.x;
  int d = dest[tok];
  if (d < 0) return;
  int b = tok >> 9;
  int j = threadIdx.x * 4;
  f16x4 v = *(const f16x4*)&hb[(size_t)tok * H_ + j];
  float4 o = {(float)v[0], (float)v[1], (float)v[2], (float)v[3]};
  *(float4*)&compact[((size_t)(b * S_ + d)) * H_ + j] = o;
}

// ---------------- classifier + softmax: one wave per token ----------------
__global__ __launch_bounds__(256) void cls_kernel(
    const float* __restrict__ x, const float* __restrict__ W,
    const float* __restrict__ bias2, float* __restrict__ out) {
  int lane = threadIdx.x & 63, wv = threadIdx.x >> 6;
  int tok = blockIdx.x * 4 + wv;
  float acc[NL_] = {};
  for (int hh = lane; hh < H_; hh += 64) {
    float xv = x[(size_t)tok * H_ + hh];
#pragma unroll
    for (int n = 0; n < NL_; ++n) acc[n] = fmaf(xv, W[hh * NL_ + n], acc[n]);
  }
#pragma unroll
  for (int n = 0; n < NL_; ++n) {
#pragma unroll
    for (int off = 32; off; off >>= 1) acc[n] += __shfl_down(acc[n], off);
  }
  if (lane == 0) {
    float vls[NL_], mx = -1e30f;
#pragma unroll
    for (int n = 0; n < NL_; ++n) {
      vls[n] = acc[n] + bias2[n];
      mx = fmaxf(mx, vls[n]);
    }
    float s = 0.f;
#pragma unroll
    for (int n = 0; n < NL_; ++n) {
      vls[n] = expf(vls[n] - mx);
      s += vls[n];
    }
    float inv = 1.0f / s;
#pragma unroll
    for (int n = 0; n < NL_; ++n) out[(size_t)tok * NL_ + n] = vls[n] * inv;
  }
}

extern "C" void kernel_launch(void* const* d_in, const int* in_sizes, int n_in,
                              void* d_out, int out_size, void* d_ws, size_t ws_size,
                              hipStream_t stream) {
  const int* wid = (const int*)d_in[0];
  const int* mask = (const int*)d_in[1];
  const int* tpid = (const int*)d_in[2];
  const int* valid = (const int*)d_in[3];
  const float* we = (const float*)d_in[4];
  const float* pe = (const float*)d_in[5];
  const float* te = (const float*)d_in[6];
  const float* eg = (const float*)d_in[7];
  const float* eb = (const float*)d_in[8];
  const float* Wq = (const float*)d_in[9];
  const float* bq = (const float*)d_in[10];
  const float* Wk = (const float*)d_in[11];
  const float* bk = (const float*)d_in[12];
  const float* Wv = (const float*)d_in[13];
  const float* bv = (const float*)d_in[14];
  const float* Wo = (const float*)d_in[15];
  const float* bo = (const float*)d_in[16];
  const float* g1 = (const float*)d_in[17];
  const float* gb1 = (const float*)d_in[18];
  const float* W1 = (const float*)d_in[19];
  const float* bf1 = (const float*)d_in[20];
  const float* W2 = (const float*)d_in[21];
  const float* bf2 = (const float*)d_in[22];
  const float* g2 = (const float*)d_in[23];
  const float* gb2 = (const float*)d_in[24];
  const float* cW = (const float*)d_in[25];
  const float* cb = (const float*)d_in[26];
  float* out = (float*)d_out;

  const size_t TOK = (size_t)B_ * S_;  // 8192
  char* ws = (char*)d_ws;
  _Float16* hb = (_Float16*)(ws + 25165824);          // 12,582,912 B (residual stream)
  _Float16* t1h = (_Float16*)(ws + 37748736);         // 12,582,912 B (x = delta+res, f16)
  char* un1 = ws + 62914560;                          // 50,331,648 B union
  _Float16* qkv = (_Float16*)un1;                     // [8192][2304] = 37,748,736 B
  _Float16* vt = (_Float16*)(un1 + 37748736);         // 12,582,912 B
  _Float16* ffh = (_Float16*)un1;                     // overlays qkv/vt after attn
  float* compactf = (float*)un1;                      // reused after layers (25MB)
  _Float16* ctx = (_Float16*)(ws + 113246208);        // 12,582,912 B
  char* wbuf = ws + 125829120;                        // 14,155,776 B
  _Float16* wqT = (_Float16*)wbuf;                    // [2304][768] fused (q,k,v rows)
  _Float16* wkT = (_Float16*)(wbuf + 1179648);
  _Float16* wvT = (_Float16*)(wbuf + 2359296);
  _Float16* woT = (_Float16*)(wbuf + 3538944);
  _Float16* w1T = (_Float16*)(wbuf + 4718592);
  _Float16* w2T = (_Float16*)(wbuf + 9437184);
  int* dest = (int*)(ws + 139984896);                 // 32,768 B
  float* qkvb = (float*)(ws + 140017664);             // 9,216 B

  dim3 blk(256);
  dim3 blk192(192);
  dim3 blk128(128);
  embed_ln_kernel<<<dim3((unsigned)TOK), blk, 0, stream>>>(wid, tpid, we, pe, te, eg, eb, hb);

  dim3 gQKV64(QKV_ / 128, TOK / 64);  // (18, 128) = 2304 blocks = 3 exact rounds @3/CU
  dim3 gH64(H_ / 128, TOK / 64);      // (6, 128)  = 768 blocks  = 1 round, all co-resident
  dim3 gF(FF_ / 128, TOK / 128);      // (24, 64)  = 1536 blocks = 3 exact rounds @2/CU
  for (int l = 0; l < L_; ++l) {
    convert_weights_kernel<<<dim3(1729), blk, 0, stream>>>(
        Wq + (size_t)l * H_ * H_, Wk + (size_t)l * H_ * H_,
        Wv + (size_t)l * H_ * H_, Wo + (size_t)l * H_ * H_,
        W1 + (size_t)l * H_ * FF_, W2 + (size_t)l * FF_ * H_,
        wqT, wkT, wvT, woT, w1T, w2T,
        bq + l * H_, bk + l * H_, bv + l * H_, qkvb);
    gemm64<1><<<gQKV64, blk128, 0, stream>>>(hb, wqT, qkvb, qkv, (int)TOK, QKV_, H_, nullptr);
    vtrans_kernel<<<dim3(S_ / 64, B_ * NH_), blk, 0, stream>>>(qkv + 2 * H_, QKV_, vt);
    flash_attn_kernel<<<dim3(S_ / 64, NH_, B_), blk, 0, stream>>>(
        qkv, qkv + H_, vt, QKV_, mask, ctx);
    // x = ctx @ Wo + bo + hb  (f16)
    gemm64<3><<<gH64, blk128, 0, stream>>>(ctx, woT, bo + l * H_, t1h, (int)TOK, H_, H_, hb);
    ln_f16_kernel<<<dim3((unsigned)TOK), blk192, 0, stream>>>(t1h, g1 + l * H_, gb1 + l * H_, hb);
    gemm_f16<2><<<gF, blk, 0, stream>>>(hb, w1T, bf1 + l * FF_, ffh, (int)TOK, FF_, H_, nullptr);
    // x = ffh @ W2 + b2 + hb  (f16)
    gemm64<3><<<gH64, blk128, 0, stream>>>(ffh, w2T, bf2 + l * H_, t1h, (int)TOK, H_, FF_, hb);
    ln_f16_kernel<<<dim3((unsigned)TOK), blk192, 0, stream>>>(t1h, g2 + l * H_, gb2 + l * H_, hb);
  }

  compact_idx_kernel<<<1, 64, 0, stream>>>(valid, dest);
  hipMemsetAsync(compactf, 0, TOK * H_ * sizeof(float), stream);
  scatter_kernel<<<dim3((unsigned)TOK), blk192, 0, stream>>>(hb, dest, compactf);
  cls_kernel<<<dim3((unsigned)(TOK / 4)), blk, 0, stream>>>(compactf, cW, cb, out);
}